// Round 3
// baseline (16831.441 us; speedup 1.0000x reference)
//
#include <hip/hip_runtime.h>

#define D      1024
#define BSZ    512
#define MC     256
#define NBK    64
#define NPAN   16
#define N_ROUNDS 3
#define MAXIT  30
#define TOLV   0.01f
#define RHOV   3.0f
#define XRHOV  0.5f
#define SPLITK 8
#define GRID   256

struct KArgs {
  const float *c, *A, *b, *AA, *L, *Lam;
  float *yout, *F, *Ybuf, *Wm, *up;  // up aliases CT (CT dead after residual)
  float *t, *q, *err;
  int *perm;
  unsigned *cnt, *gen;
};

// ---------------- manual grid barrier (agent scope, works across XCDs) ----------------
__device__ __forceinline__ void gbar(unsigned* cnt, unsigned* gen) {
  __syncthreads();
  if (threadIdx.x == 0) {
    __builtin_amdgcn_fence(__ATOMIC_RELEASE, "agent");
    const unsigned g0 = __hip_atomic_load(gen, __ATOMIC_ACQUIRE, __HIP_MEMORY_SCOPE_AGENT);
    const unsigned arrived =
        __hip_atomic_fetch_add(cnt, 1u, __ATOMIC_ACQ_REL, __HIP_MEMORY_SCOPE_AGENT) + 1u;
    if (arrived == GRID) {
      __hip_atomic_store(cnt, 0u, __ATOMIC_RELAXED, __HIP_MEMORY_SCOPE_AGENT);
      __hip_atomic_fetch_add(gen, 1u, __ATOMIC_RELEASE, __HIP_MEMORY_SCOPE_AGENT);
    } else {
      while (__hip_atomic_load(gen, __ATOMIC_RELAXED, __HIP_MEMORY_SCOPE_AGENT) == g0)
        __builtin_amdgcn_s_sleep(4);
    }
    __builtin_amdgcn_fence(__ATOMIC_ACQUIRE, "agent");
  }
  __syncthreads();
}

// ---------------- shared tile FMA (64x64 tile, 4x4 per thread) ----------------
__device__ __forceinline__ void tile_fma(const float (*As)[68], const float (*Bs)[68],
                                         float acc[4][4], const int tx, const int ty) {
#pragma unroll 8
  for (int kk = 0; kk < 64; ++kk) {
    const float4 a4 = *(const float4*)(&As[kk][ty * 4]);
    const float4 b4 = *(const float4*)(&Bs[kk][tx * 4]);
    const float a0 = a4.x, a1 = a4.y, a2 = a4.z, a3 = a4.w;
    const float b0 = b4.x, b1 = b4.y, b2 = b4.z, b3 = b4.w;
    acc[0][0] = fmaf(a0, b0, acc[0][0]); acc[0][1] = fmaf(a0, b1, acc[0][1]);
    acc[0][2] = fmaf(a0, b2, acc[0][2]); acc[0][3] = fmaf(a0, b3, acc[0][3]);
    acc[1][0] = fmaf(a1, b0, acc[1][0]); acc[1][1] = fmaf(a1, b1, acc[1][1]);
    acc[1][2] = fmaf(a1, b2, acc[1][2]); acc[1][3] = fmaf(a1, b3, acc[1][3]);
    acc[2][0] = fmaf(a2, b0, acc[2][0]); acc[2][1] = fmaf(a2, b1, acc[2][1]);
    acc[2][2] = fmaf(a2, b2, acc[2][2]); acc[2][3] = fmaf(a2, b3, acc[2][3]);
    acc[3][0] = fmaf(a3, b0, acc[3][0]); acc[3][1] = fmaf(a3, b1, acc[3][1]);
    acc[3][2] = fmaf(a3, b2, acc[3][2]); acc[3][3] = fmaf(a3, b3, acc[3][3]);
  }
}

// ---------------- phases (bodies identical to verified round-1 kernels) ----------------

__device__ void ph_prep(float* sm, int vb, const float* L, const float* Lam,
                        float* F, float* Ybuf, float* CT) {
  float (*tile)[65] = (float(*)[65])sm;
  const int bi = vb >> 4, bj = vb & 15;
  const int tx = threadIdx.x & 63, ty4 = threadIdx.x >> 6;
  const int i0 = bi * 64, j0 = bj * 64;
  for (int r = ty4; r < 64; r += 4) {
    const float v = L[(size_t)(i0 + r) * D + j0 + tx];
    F[(size_t)(i0 + r) * D + j0 + tx] = v;
    tile[r][tx] = v;
  }
  __syncthreads();
  for (int r = ty4; r < 64; r += 4) {
    const int j = j0 + r;
    const float val = Lam[j] * tile[tx][r];
    Ybuf[(size_t)j * D + i0 + tx] = val;
    CT[(size_t)j * D + i0 + tx] = val;
  }
  __syncthreads();
}

__device__ void ph_lu_diag(float* sm, float* F, int* perm, int k) {
  float (*blk)[65] = (float(*)[65])sm;
  int* pr_sh = (int*)&sm[8960];
  const int tid = threadIdx.x;
  const int c0 = k * NBK;
  for (int e = tid; e < 4096; e += 256) {
    const int r = e >> 6, c = e & 63;
    blk[r][c] = F[(size_t)(c0 + r) * D + c0 + c];
  }
  __syncthreads();
  for (int j = 0; j < 64; ++j) {
    if (tid < 64) {
      float v = (tid >= j) ? fabsf(blk[tid][j]) : -1.0f;
      int ridx = tid;
      for (int off = 32; off > 0; off >>= 1) {
        const float ov = __shfl_down(v, off);
        const int oi = __shfl_down(ridx, off);
        if (ov > v) { v = ov; ridx = oi; }
      }
      if (tid == 0) *pr_sh = ridx;
    }
    __syncthreads();
    const int pr = *pr_sh;
    if (pr != j) {
      if (tid < 64) { const float a = blk[j][tid], b = blk[pr][tid]; blk[j][tid] = b; blk[pr][tid] = a; }
      if (tid == 0) { const int t = perm[c0 + j]; perm[c0 + j] = perm[c0 + pr]; perm[c0 + pr] = t; }
    }
    __syncthreads();
    if (pr != j) {
      for (int c = tid; c < D; c += 256) {
        if (c >= c0 && c < c0 + 64) continue;
        const float a = F[(size_t)(c0 + j) * D + c], b = F[(size_t)(c0 + pr) * D + c];
        F[(size_t)(c0 + j) * D + c] = b;
        F[(size_t)(c0 + pr) * D + c] = a;
      }
    }
    const float inv = 1.0f / blk[j][j];
    const int r = tid >> 2, l4 = tid & 3;
    if (r > j) {
      const float lval = blk[r][j] * inv;
      if (l4 == 0) blk[r][j] = lval;
      for (int c = j + 1 + l4; c < 64; c += 4)
        blk[r][c] = fmaf(-lval, blk[j][c], blk[r][c]);
    }
    __syncthreads();
  }
  for (int e = tid; e < 4096; e += 256) {
    const int r = e >> 6, c = e & 63;
    F[(size_t)(c0 + r) * D + c0 + c] = blk[r][c];
  }
  __syncthreads();
}

__device__ void ph_l21(float* sm, float* F, int k, int vb) {
  const int c0 = k * NBK;
  const int row0 = c0 + NBK;
  const int nrows = D - row0;
  float (*U)[65] = (float(*)[65])sm;
  const int tid = threadIdx.x;
  for (int e = tid; e < 4096; e += 256) { const int r = e >> 6, c = e & 63; U[r][c] = F[(size_t)(c0 + r) * D + c0 + c]; }
  __syncthreads();
  const int r = vb * 256 + tid;
  if (r >= nrows) return;
  float* Arow = &F[(size_t)(row0 + r) * D + c0];
  float x[64];
#pragma unroll
  for (int jj = 0; jj < 64; ++jj) {
    float s0 = 0.f, s1 = 0.f, s2 = 0.f, s3 = 0.f;
#pragma unroll
    for (int i = 0; i + 3 < jj; i += 4) {
      s0 = fmaf(x[i], U[i][jj], s0);
      s1 = fmaf(x[i + 1], U[i + 1][jj], s1);
      s2 = fmaf(x[i + 2], U[i + 2][jj], s2);
      s3 = fmaf(x[i + 3], U[i + 3][jj], s3);
    }
#pragma unroll
    for (int i = (jj / 4) * 4; i < jj; ++i) s0 = fmaf(x[i], U[i][jj], s0);
    const float a = Arow[jj] - ((s0 + s1) + (s2 + s3));
    x[jj] = a / U[jj][jj];
    Arow[jj] = x[jj];
  }
}

__device__ void ph_trsm(float* sm, float* F, int k, int vb) {
  const int c0 = k * NBK;
  const int colstart = c0 + NBK;
  const int ncols = D - colstart;
  float (*Lw)[65] = (float(*)[65])sm;
  const int tid = threadIdx.x;
  for (int e = tid; e < 4096; e += 256) { const int r = e >> 6, c = e & 63; Lw[r][c] = F[(size_t)(c0 + r) * D + c0 + c]; }
  __syncthreads();
  const int cidx = vb * 256 + tid;
  if (cidx >= ncols) return;
  const int col = colstart + cidx;
  float x[64];
#pragma unroll
  for (int i = 0; i < 64; ++i) {
    float s0 = 0.f, s1 = 0.f, s2 = 0.f, s3 = 0.f;
#pragma unroll
    for (int j = 0; j + 3 < i; j += 4) {
      s0 = fmaf(Lw[i][j], x[j], s0);
      s1 = fmaf(Lw[i][j + 1], x[j + 1], s1);
      s2 = fmaf(Lw[i][j + 2], x[j + 2], s2);
      s3 = fmaf(Lw[i][j + 3], x[j + 3], s3);
    }
#pragma unroll
    for (int j = (i / 4) * 4; j < i; ++j) s0 = fmaf(Lw[i][j], x[j], s0);
    const float a = F[(size_t)(c0 + i) * D + col] - ((s0 + s1) + (s2 + s3));
    x[i] = a;
    F[(size_t)(c0 + i) * D + col] = a;
  }
}

__device__ void ph_gemm_nn(float* sm, float* F, int k, int vbx, int vby) {
  const int c0 = k * NBK;
  const int o = c0 + NBK;
  float (*As)[68] = (float(*)[68])sm;
  float (*Bs)[68] = (float(*)[68])&sm[4352];
  const int tid = threadIdx.x;
  const int cc0 = o + vbx * 64;
  const int r0 = o + vby * 64;
  for (int e = tid; e < 4096; e += 256) {
    const int r = e >> 6, c = e & 63;
    As[c][r] = F[(size_t)(r0 + r) * D + c0 + c];
    Bs[r][c] = F[(size_t)(c0 + r) * D + cc0 + c];
  }
  __syncthreads();
  float acc[4][4] = {};
  tile_fma(As, Bs, acc, tid & 15, tid >> 4);
  const int tx = tid & 15, ty = tid >> 4;
  for (int i = 0; i < 4; ++i)
    for (int j = 0; j < 4; ++j)
      F[(size_t)(r0 + ty * 4 + i) * D + cc0 + tx * 4 + j] -= acc[i][j];
  __syncthreads();
}

__device__ void ph_fsolve(float* sm, const float* F, float* Y, int k, int vb) {
  float (*T)[65] = (float(*)[65])sm;  // T[i][j] = U[c0+j][c0+i]
  const int tid = threadIdx.x;
  const int c0 = k * NBK;
  for (int e = tid; e < 4096; e += 256) { const int r = e >> 6, c = e & 63; T[c][r] = F[(size_t)(c0 + r) * D + c0 + c]; }
  __syncthreads();
  const int col = vb * 256 + tid;
  float x[64];
#pragma unroll
  for (int i = 0; i < 64; ++i) {
    float s0 = 0.f, s1 = 0.f, s2 = 0.f, s3 = 0.f;
#pragma unroll
    for (int j = 0; j + 3 < i; j += 4) {
      s0 = fmaf(T[i][j], x[j], s0);
      s1 = fmaf(T[i][j + 1], x[j + 1], s1);
      s2 = fmaf(T[i][j + 2], x[j + 2], s2);
      s3 = fmaf(T[i][j + 3], x[j + 3], s3);
    }
#pragma unroll
    for (int j = (i / 4) * 4; j < i; ++j) s0 = fmaf(T[i][j], x[j], s0);
    const float a = Y[(size_t)(c0 + i) * D + col] - ((s0 + s1) + (s2 + s3));
    x[i] = a / T[i][i];
    Y[(size_t)(c0 + i) * D + col] = x[i];
  }
  __syncthreads();
}

__device__ void ph_bsolve(float* sm, const float* F, float* Y, int k, int vb) {
  float (*T)[65] = (float(*)[65])sm;
  const int tid = threadIdx.x;
  const int c0 = k * NBK;
  for (int e = tid; e < 4096; e += 256) { const int r = e >> 6, c = e & 63; T[c][r] = F[(size_t)(c0 + r) * D + c0 + c]; }
  __syncthreads();
  const int col = vb * 256 + tid;
  float x[64];
#pragma unroll
  for (int i = 63; i >= 0; --i) {
    float s0 = 0.f, s1 = 0.f, s2 = 0.f, s3 = 0.f;
#pragma unroll
    for (int j = i + 1; j + 3 < 64; j += 4) {
      s0 = fmaf(T[i][j], x[j], s0);
      s1 = fmaf(T[i][j + 1], x[j + 1], s1);
      s2 = fmaf(T[i][j + 2], x[j + 2], s2);
      s3 = fmaf(T[i][j + 3], x[j + 3], s3);
    }
#pragma unroll
    for (int j = i + 1 + (((63 - i) / 4) * 4); j < 64; ++j) s0 = fmaf(T[i][j], x[j], s0);
    const float a = Y[(size_t)(c0 + i) * D + col] - ((s0 + s1) + (s2 + s3));
    x[i] = a;
    Y[(size_t)(c0 + i) * D + col] = a;
  }
  __syncthreads();
}

__device__ void ph_tn(float* sm, const float* F, float* Y, int k, int rlo, int vbx, int vby) {
  const int c0 = k * NBK;
  float (*As)[68] = (float(*)[68])sm;
  float (*Bs)[68] = (float(*)[68])&sm[4352];
  const int tid = threadIdx.x;
  const int cc0 = vbx * 64;
  const int r0 = rlo + vby * 64;
  for (int e = tid; e < 4096; e += 256) {
    const int r = e >> 6, c = e & 63;
    As[r][c] = F[(size_t)(c0 + r) * D + r0 + c];
    Bs[r][c] = Y[(size_t)(c0 + r) * D + cc0 + c];
  }
  __syncthreads();
  float acc[4][4] = {};
  tile_fma(As, Bs, acc, tid & 15, tid >> 4);
  const int tx = tid & 15, ty = tid >> 4;
  for (int i = 0; i < 4; ++i)
    for (int j = 0; j < 4; ++j)
      Y[(size_t)(r0 + ty * 4 + i) * D + cc0 + tx * 4 + j] -= acc[i][j];
  __syncthreads();
}

__device__ void ph_scatter(const float* Y, float* Wm, const int* perm, int add, int vb) {
  const int i = vb >> 2;
  const int c = (vb & 3) * 256 + threadIdx.x;
  const int dst = perm[i];
  const float v = Y[(size_t)i * D + c];
  if (add) Wm[(size_t)dst * D + c] += v;
  else Wm[(size_t)dst * D + c] = v;
}

__device__ void ph_residual(float* sm, const float* Lmat, const float* Wm,
                            const float* CT, float* Y, int vbx, int vby) {
  float (*As)[68] = (float(*)[68])sm;
  float (*Bs)[68] = (float(*)[68])&sm[4352];
  const int tid = threadIdx.x;
  const int cc0 = vbx * 64;
  const int i0 = vby * 64;
  float acc[4][4] = {};
  for (int kb = 0; kb < D; kb += 64) {
    for (int e = tid; e < 4096; e += 256) {
      const int r = e >> 6, c = e & 63;
      As[r][c] = Lmat[(size_t)(kb + r) * D + i0 + c];
      Bs[r][c] = Wm[(size_t)(kb + r) * D + cc0 + c];
    }
    __syncthreads();
    tile_fma(As, Bs, acc, tid & 15, tid >> 4);
    __syncthreads();
  }
  const int tx = tid & 15, ty = tid >> 4;
  for (int i = 0; i < 4; ++i)
    for (int j = 0; j < 4; ++j) {
      const size_t idx = (size_t)(i0 + ty * 4 + i) * D + cc0 + tx * 4 + j;
      Y[idx] = CT[idx] - acc[i][j];
    }
  __syncthreads();
}

__device__ void ph_round(float* sm, const float* yout, const float* Wm, const float* cmat,
                         float* t, float* q, int vbx, int vby) {
  float (*As)[68] = (float(*)[68])sm;
  float (*Bs)[68] = (float(*)[68])&sm[4352];
  const int tid = threadIdx.x;
  const int i0 = vbx * 64;
  const int b0 = vby * 64;
  float acc[4][4] = {};
  for (int kb = 0; kb < D; kb += 64) {
    for (int e = tid; e < 4096; e += 256) {
      const int r = e >> 6, c = e & 63;
      As[c][r] = yout[(size_t)(b0 + r) * D + kb + c];
      Bs[r][c] = Wm[(size_t)(kb + r) * D + i0 + c];
    }
    __syncthreads();
    tile_fma(As, Bs, acc, tid & 15, tid >> 4);
    __syncthreads();
  }
  const int tx = tid & 15, ty = tid >> 4;
  for (int i = 0; i < 4; ++i)
    for (int j = 0; j < 4; ++j) {
      const int b = b0 + ty * 4 + i, col = i0 + tx * 4 + j;
      const float v = yout[(size_t)b * D + col] - XRHOV * acc[i][j] - RHOV * cmat[(size_t)b * D + col];
      t[(size_t)b * D + col] = v;
      q[(size_t)b * D + col] = 0.0f;
    }
  __syncthreads();
}

__device__ void ph_dykA(float* sm, const float* t, const float* Amat, float* u_part,
                        int vbm, int vbb, int z) {
  float (*As)[68] = (float(*)[68])sm;
  float (*Bs)[68] = (float(*)[68])&sm[4352];
  const int tid = threadIdx.x;
  const int m0 = vbm * 64;
  const int b0 = vbb * 64;
  float acc[4][4] = {};
  for (int kb = z * (D / SPLITK); kb < (z + 1) * (D / SPLITK); kb += 64) {
    for (int e = tid; e < 4096; e += 256) {
      const int r = e >> 6, c = e & 63;
      As[c][r] = t[(size_t)(b0 + r) * D + kb + c];
      Bs[c][r] = Amat[(size_t)(m0 + r) * D + kb + c];
    }
    __syncthreads();
    tile_fma(As, Bs, acc, tid & 15, tid >> 4);
    __syncthreads();
  }
  const int tx = tid & 15, ty = tid >> 4;
  for (int i = 0; i < 4; ++i)
    for (int j = 0; j < 4; ++j)
      u_part[(size_t)z * BSZ * MC + (size_t)(b0 + ty * 4 + i) * MC + m0 + tx * 4 + j] = acc[i][j];
  __syncthreads();
}

__device__ void ph_dykB(float* sm, float* t, float* q, float* yout,
                        const float* u_part, const float* AAm, const float* bvec,
                        float* err, int slot, int vbd, int vbb) {
  float (*As)[68] = (float(*)[68])sm;
  float (*Bs)[68] = (float(*)[68])&sm[4352];
  float* red = &sm[8704];
  const int tid = threadIdx.x;
  const int d0 = vbd * 64;
  const int b0 = vbb * 64;
  float acc[4][4] = {};
  for (int kb = 0; kb < MC; kb += 64) {
    for (int e = tid; e < 4096; e += 256) {
      const int r = e >> 6, c = e & 63;
      const size_t ub = (size_t)(b0 + r) * MC + kb + c;
      float uv = -bvec[kb + c];
#pragma unroll
      for (int z = 0; z < SPLITK; ++z) uv += u_part[(size_t)z * BSZ * MC + ub];
      As[c][r] = uv;
      Bs[c][r] = AAm[(size_t)(d0 + r) * MC + kb + c];
    }
    __syncthreads();
    tile_fma(As, Bs, acc, tid & 15, tid >> 4);
    __syncthreads();
  }
  const int tx = tid & 15, ty = tid >> 4;
  float nmax = 0.0f;
  for (int i = 0; i < 4; ++i) {
    const int b = b0 + ty * 4 + i;
    for (int j = 0; j < 4; ++j) {
      const int d = d0 + tx * 4 + j;
      const size_t idx = (size_t)b * D + d;
      const float tv = t[idx];
      const float y = tv - acc[i][j];
      yout[idx] = y;
      const float qv = q[idx];
      const float yq = y + qv;
      const float xn = fmaxf(yq, 0.0f);
      t[idx] = xn + (tv - y);
      q[idx] = yq - xn;
      nmax = fmaxf(nmax, -y);
    }
  }
  red[tid] = nmax;
  __syncthreads();
  for (int s = 128; s > 0; s >>= 1) {
    if (tid < s) red[tid] = fmaxf(red[tid], red[tid + s]);
    __syncthreads();
  }
  if (tid == 0) atomicMax((int*)&err[slot], __float_as_int(red[0]));
  __syncthreads();
}

// ---------------- the megakernel (plain launch + manual grid barrier) ----------------
__global__ __launch_bounds__(256, 1) void mega(KArgs a) {
  __shared__ alignas(16) float sm[8964];
  const int bid = blockIdx.x;
  const int tid = threadIdx.x;
  unsigned* cnt = a.cnt;
  unsigned* gen = a.gen;

  // phase 0: init t=-rho*c, q=0, perm; prep F/CT/Ybuf  (err/cnt/gen zeroed by host memset)
  {
    const int gtid = bid * 256 + tid;
    for (int i = gtid; i < BSZ * D; i += GRID * 256) {
      a.t[i] = -RHOV * a.c[i];
      a.q[i] = 0.0f;
    }
    if (gtid < D) a.perm[gtid] = gtid;
  }
  for (int vb = bid; vb < 256; vb += GRID) ph_prep(sm, vb, a.L, a.Lam, a.F, a.Ybuf, a.up);
  gbar(cnt, gen);

  // blocked LU with block-local partial pivoting
  for (int k = 0; k < NPAN; ++k) {
    if (bid == 0) ph_lu_diag(sm, a.F, a.perm, k);
    gbar(cnt, gen);
    const int rem = D - (k + 1) * NBK;
    if (rem > 0) {
      const int nvb = (rem + 255) / 256;
      for (int vb = bid; vb < 2 * nvb; vb += GRID) {
        if (vb < nvb) ph_l21(sm, a.F, k, vb);
        else ph_trsm(sm, a.F, k, vb - nvb);
      }
      gbar(cnt, gen);
      const int nt = rem / 64;
      for (int vb = bid; vb < nt * nt; vb += GRID) ph_gemm_nn(sm, a.F, k, vb % nt, vb / nt);
      gbar(cnt, gen);
    }
  }

  // two solve passes (pass 1 = iterative refinement)
  for (int pass = 0; pass < 2; ++pass) {
    for (int k = 0; k < NPAN; ++k) {
      for (int vb = bid; vb < 4; vb += GRID) ph_fsolve(sm, a.F, a.Ybuf, k, vb);
      gbar(cnt, gen);
      const int rem = D - (k + 1) * NBK;
      if (rem > 0) {
        for (int vb = bid; vb < 16 * (rem / 64); vb += GRID)
          ph_tn(sm, a.F, a.Ybuf, k, (k + 1) * NBK, vb & 15, vb >> 4);
        gbar(cnt, gen);
      }
    }
    for (int k = NPAN - 1; k >= 0; --k) {
      for (int vb = bid; vb < 4; vb += GRID) ph_bsolve(sm, a.F, a.Ybuf, k, vb);
      gbar(cnt, gen);
      if (k > 0) {
        for (int vb = bid; vb < 16 * k; vb += GRID)
          ph_tn(sm, a.F, a.Ybuf, k, 0, vb & 15, vb >> 4);
        gbar(cnt, gen);
      }
    }
    for (int vb = bid; vb < 4 * D; vb += GRID) ph_scatter(a.Ybuf, a.Wm, a.perm, pass, vb);
    gbar(cnt, gen);
    if (pass == 0) {
      for (int vb = bid; vb < 256; vb += GRID)
        ph_residual(sm, a.L, a.Wm, a.up, a.Ybuf, vb & 15, vb >> 4);
      gbar(cnt, gen);
    }
  }

  // 3 rounds of step + Dykstra with uniform early exit
  for (int r = 0; r < N_ROUNDS; ++r) {
    if (r > 0) {
      for (int vb = bid; vb < 128; vb += GRID)
        ph_round(sm, a.yout, a.Wm, a.c, a.t, a.q, vb & 15, vb >> 4);
      gbar(cnt, gen);
    }
    const int base = r * MAXIT;
    for (int it = 0; it < MAXIT; ++it) {
      for (int vb = bid; vb < 4 * 8 * SPLITK; vb += GRID)
        ph_dykA(sm, a.t, a.A, a.up, vb & 3, (vb >> 2) & 7, vb >> 5);
      gbar(cnt, gen);
      for (int vb = bid; vb < 128; vb += GRID)
        ph_dykB(sm, a.t, a.q, a.yout, a.up, a.AA, a.b, a.err, base + it, vb & 15, vb >> 4);
      gbar(cnt, gen);
      const int eb = __hip_atomic_load((int*)&a.err[base + it], __ATOMIC_RELAXED,
                                       __HIP_MEMORY_SCOPE_AGENT);
      if (__int_as_float(eb) < TOLV) break;  // uniform across grid: read after barrier
    }
  }
}

extern "C" void kernel_launch(void* const* d_in, const int* in_sizes, int n_in,
                              void* d_out, int out_size, void* d_ws, size_t ws_size,
                              hipStream_t stream) {
  (void)in_sizes; (void)n_in; (void)out_size; (void)ws_size;
  KArgs a;
  a.c   = (const float*)d_in[0];
  a.A   = (const float*)d_in[1];
  a.b   = (const float*)d_in[2];
  a.AA  = (const float*)d_in[3];
  a.L   = (const float*)d_in[4];
  a.Lam = (const float*)d_in[5];
  a.yout = (float*)d_out;

  // ctrl region (zeroed every call; ws is NOT re-poisoned between replays)
  char* w = (char*)d_ws;
  a.cnt  = (unsigned*)w;            // [0]
  a.gen  = (unsigned*)(w + 4);      // [1]
  a.err  = (float*)(w + 64);        // 90 slots
  w += 4096;
  a.F    = (float*)w; w += (size_t)D * D * 4;
  a.Ybuf = (float*)w; w += (size_t)D * D * 4;
  a.Wm   = (float*)w; w += (size_t)D * D * 4;
  a.up   = (float*)w; w += (size_t)SPLITK * BSZ * MC * 4;  // 4MB, doubles as CT
  a.t    = (float*)w; w += (size_t)BSZ * D * 4;
  a.q    = (float*)w; w += (size_t)BSZ * D * 4;
  a.perm = (int*)w;   w += D * 4;

  hipMemsetAsync(d_ws, 0, 4096, stream);
  mega<<<dim3(GRID), dim3(256), 0, stream>>>(a);
}

// Round 4
// 16404.976 us; speedup vs baseline: 1.0260x; 1.0260x over previous
//
#include <hip/hip_runtime.h>

#define D      1024
#define BSZ    512
#define MC     256
#define NBK    64
#define NPAN   16
#define N_ROUNDS 3
#define MAXIT  30
#define TOLV   0.01f
#define RHOV   3.0f
#define XRHOV  0.5f
#define GRID   256

struct KArgs {
  const float *c, *A, *b, *AA, *L, *Lam;
  float *yout, *F, *Ybuf, *Wm, *CT;
  float *t, *q, *err;
  int *perm;
  unsigned *arrive, *gen;
};

// ---------------- multi-slot grid barrier (no RMW contention) ----------------
// Each block stores a monotone generation to its own 64B slot; block 0's 256
// threads poll all 256 slots in parallel, then publish gen; all blocks poll gen.
__device__ __forceinline__ void gbar(unsigned* arrive, unsigned* gen, unsigned& bgen) {
  __syncthreads();
  bgen += 1u;
  const unsigned target = bgen;
  if (threadIdx.x == 0) {
    __builtin_amdgcn_fence(__ATOMIC_RELEASE, "agent");
    __hip_atomic_store(&arrive[blockIdx.x * 16], target, __ATOMIC_RELAXED,
                       __HIP_MEMORY_SCOPE_AGENT);
  }
  if (blockIdx.x == 0) {
    while (__hip_atomic_load(&arrive[threadIdx.x * 16], __ATOMIC_RELAXED,
                             __HIP_MEMORY_SCOPE_AGENT) < target)
      __builtin_amdgcn_s_sleep(1);
    __builtin_amdgcn_fence(__ATOMIC_ACQUIRE, "agent");
    __syncthreads();
    if (threadIdx.x == 0)
      __hip_atomic_store(gen, target, __ATOMIC_RELEASE, __HIP_MEMORY_SCOPE_AGENT);
  }
  if (threadIdx.x == 0) {
    while (__hip_atomic_load(gen, __ATOMIC_RELAXED, __HIP_MEMORY_SCOPE_AGENT) < target)
      __builtin_amdgcn_s_sleep(1);
    __builtin_amdgcn_fence(__ATOMIC_ACQUIRE, "agent");
  }
  __syncthreads();
}

// ---------------- shared tile FMA (64x64 tile, 4x4 per thread) ----------------
__device__ __forceinline__ void tile_fma(const float (*As)[68], const float (*Bs)[68],
                                         float acc[4][4], const int tx, const int ty) {
#pragma unroll 8
  for (int kk = 0; kk < 64; ++kk) {
    const float4 a4 = *(const float4*)(&As[kk][ty * 4]);
    const float4 b4 = *(const float4*)(&Bs[kk][tx * 4]);
    const float a0 = a4.x, a1 = a4.y, a2 = a4.z, a3 = a4.w;
    const float b0 = b4.x, b1 = b4.y, b2 = b4.z, b3 = b4.w;
    acc[0][0] = fmaf(a0, b0, acc[0][0]); acc[0][1] = fmaf(a0, b1, acc[0][1]);
    acc[0][2] = fmaf(a0, b2, acc[0][2]); acc[0][3] = fmaf(a0, b3, acc[0][3]);
    acc[1][0] = fmaf(a1, b0, acc[1][0]); acc[1][1] = fmaf(a1, b1, acc[1][1]);
    acc[1][2] = fmaf(a1, b2, acc[1][2]); acc[1][3] = fmaf(a1, b3, acc[1][3]);
    acc[2][0] = fmaf(a2, b0, acc[2][0]); acc[2][1] = fmaf(a2, b1, acc[2][1]);
    acc[2][2] = fmaf(a2, b2, acc[2][2]); acc[2][3] = fmaf(a2, b3, acc[2][3]);
    acc[3][0] = fmaf(a3, b0, acc[3][0]); acc[3][1] = fmaf(a3, b1, acc[3][1]);
    acc[3][2] = fmaf(a3, b2, acc[3][2]); acc[3][3] = fmaf(a3, b3, acc[3][3]);
  }
}

// ---------------- phases (LU/solve bodies identical to verified round-1) ----------------

__device__ void ph_prep(float* sm, int vb, const float* L, const float* Lam,
                        float* F, float* Ybuf, float* CT) {
  float (*tile)[65] = (float(*)[65])sm;
  const int bi = vb >> 4, bj = vb & 15;
  const int tx = threadIdx.x & 63, ty4 = threadIdx.x >> 6;
  const int i0 = bi * 64, j0 = bj * 64;
  for (int r = ty4; r < 64; r += 4) {
    const float v = L[(size_t)(i0 + r) * D + j0 + tx];
    F[(size_t)(i0 + r) * D + j0 + tx] = v;
    tile[r][tx] = v;
  }
  __syncthreads();
  for (int r = ty4; r < 64; r += 4) {
    const int j = j0 + r;
    const float val = Lam[j] * tile[tx][r];
    Ybuf[(size_t)j * D + i0 + tx] = val;
    CT[(size_t)j * D + i0 + tx] = val;
  }
  __syncthreads();
}

__device__ void ph_lu_diag(float* sm, float* F, int* perm, int k) {
  float (*blk)[65] = (float(*)[65])sm;
  int* pr_sh = (int*)&sm[8960];
  const int tid = threadIdx.x;
  const int c0 = k * NBK;
  for (int e = tid; e < 4096; e += 256) {
    const int r = e >> 6, c = e & 63;
    blk[r][c] = F[(size_t)(c0 + r) * D + c0 + c];
  }
  __syncthreads();
  for (int j = 0; j < 64; ++j) {
    if (tid < 64) {
      float v = (tid >= j) ? fabsf(blk[tid][j]) : -1.0f;
      int ridx = tid;
      for (int off = 32; off > 0; off >>= 1) {
        const float ov = __shfl_down(v, off);
        const int oi = __shfl_down(ridx, off);
        if (ov > v) { v = ov; ridx = oi; }
      }
      if (tid == 0) *pr_sh = ridx;
    }
    __syncthreads();
    const int pr = *pr_sh;
    if (pr != j) {
      if (tid < 64) { const float a = blk[j][tid], b = blk[pr][tid]; blk[j][tid] = b; blk[pr][tid] = a; }
      if (tid == 0) { const int t = perm[c0 + j]; perm[c0 + j] = perm[c0 + pr]; perm[c0 + pr] = t; }
    }
    __syncthreads();
    if (pr != j) {
      for (int c = tid; c < D; c += 256) {
        if (c >= c0 && c < c0 + 64) continue;
        const float a = F[(size_t)(c0 + j) * D + c], b = F[(size_t)(c0 + pr) * D + c];
        F[(size_t)(c0 + j) * D + c] = b;
        F[(size_t)(c0 + pr) * D + c] = a;
      }
    }
    const float inv = 1.0f / blk[j][j];
    const int r = tid >> 2, l4 = tid & 3;
    if (r > j) {
      const float lval = blk[r][j] * inv;
      if (l4 == 0) blk[r][j] = lval;
      for (int c = j + 1 + l4; c < 64; c += 4)
        blk[r][c] = fmaf(-lval, blk[j][c], blk[r][c]);
    }
    __syncthreads();
  }
  for (int e = tid; e < 4096; e += 256) {
    const int r = e >> 6, c = e & 63;
    F[(size_t)(c0 + r) * D + c0 + c] = blk[r][c];
  }
  __syncthreads();
}

__device__ void ph_l21(float* sm, float* F, int k, int vb) {
  const int c0 = k * NBK;
  const int row0 = c0 + NBK;
  const int nrows = D - row0;
  float (*U)[65] = (float(*)[65])sm;
  const int tid = threadIdx.x;
  for (int e = tid; e < 4096; e += 256) { const int r = e >> 6, c = e & 63; U[r][c] = F[(size_t)(c0 + r) * D + c0 + c]; }
  __syncthreads();
  const int r = vb * 256 + tid;
  if (r >= nrows) return;
  float* Arow = &F[(size_t)(row0 + r) * D + c0];
  float x[64];
#pragma unroll
  for (int jj = 0; jj < 64; ++jj) {
    float s0 = 0.f, s1 = 0.f, s2 = 0.f, s3 = 0.f;
#pragma unroll
    for (int i = 0; i + 3 < jj; i += 4) {
      s0 = fmaf(x[i], U[i][jj], s0);
      s1 = fmaf(x[i + 1], U[i + 1][jj], s1);
      s2 = fmaf(x[i + 2], U[i + 2][jj], s2);
      s3 = fmaf(x[i + 3], U[i + 3][jj], s3);
    }
#pragma unroll
    for (int i = (jj / 4) * 4; i < jj; ++i) s0 = fmaf(x[i], U[i][jj], s0);
    const float a = Arow[jj] - ((s0 + s1) + (s2 + s3));
    x[jj] = a / U[jj][jj];
    Arow[jj] = x[jj];
  }
}

__device__ void ph_trsm(float* sm, float* F, int k, int vb) {
  const int c0 = k * NBK;
  const int colstart = c0 + NBK;
  const int ncols = D - colstart;
  float (*Lw)[65] = (float(*)[65])sm;
  const int tid = threadIdx.x;
  for (int e = tid; e < 4096; e += 256) { const int r = e >> 6, c = e & 63; Lw[r][c] = F[(size_t)(c0 + r) * D + c0 + c]; }
  __syncthreads();
  const int cidx = vb * 256 + tid;
  if (cidx >= ncols) return;
  const int col = colstart + cidx;
  float x[64];
#pragma unroll
  for (int i = 0; i < 64; ++i) {
    float s0 = 0.f, s1 = 0.f, s2 = 0.f, s3 = 0.f;
#pragma unroll
    for (int j = 0; j + 3 < i; j += 4) {
      s0 = fmaf(Lw[i][j], x[j], s0);
      s1 = fmaf(Lw[i][j + 1], x[j + 1], s1);
      s2 = fmaf(Lw[i][j + 2], x[j + 2], s2);
      s3 = fmaf(Lw[i][j + 3], x[j + 3], s3);
    }
#pragma unroll
    for (int j = (i / 4) * 4; j < i; ++j) s0 = fmaf(Lw[i][j], x[j], s0);
    const float a = F[(size_t)(c0 + i) * D + col] - ((s0 + s1) + (s2 + s3));
    x[i] = a;
    F[(size_t)(c0 + i) * D + col] = a;
  }
}

__device__ void ph_gemm_nn(float* sm, float* F, int k, int vbx, int vby) {
  const int c0 = k * NBK;
  const int o = c0 + NBK;
  float (*As)[68] = (float(*)[68])sm;
  float (*Bs)[68] = (float(*)[68])&sm[4352];
  const int tid = threadIdx.x;
  const int cc0 = o + vbx * 64;
  const int r0 = o + vby * 64;
  for (int e = tid; e < 4096; e += 256) {
    const int r = e >> 6, c = e & 63;
    As[c][r] = F[(size_t)(r0 + r) * D + c0 + c];
    Bs[r][c] = F[(size_t)(c0 + r) * D + cc0 + c];
  }
  __syncthreads();
  float acc[4][4] = {};
  tile_fma(As, Bs, acc, tid & 15, tid >> 4);
  const int tx = tid & 15, ty = tid >> 4;
  for (int i = 0; i < 4; ++i)
    for (int j = 0; j < 4; ++j)
      F[(size_t)(r0 + ty * 4 + i) * D + cc0 + tx * 4 + j] -= acc[i][j];
  __syncthreads();
}

__device__ void ph_fsolve(float* sm, const float* F, float* Y, int k, int vb) {
  float (*T)[65] = (float(*)[65])sm;
  const int tid = threadIdx.x;
  const int c0 = k * NBK;
  for (int e = tid; e < 4096; e += 256) { const int r = e >> 6, c = e & 63; T[c][r] = F[(size_t)(c0 + r) * D + c0 + c]; }
  __syncthreads();
  const int col = vb * 256 + tid;
  float x[64];
#pragma unroll
  for (int i = 0; i < 64; ++i) {
    float s0 = 0.f, s1 = 0.f, s2 = 0.f, s3 = 0.f;
#pragma unroll
    for (int j = 0; j + 3 < i; j += 4) {
      s0 = fmaf(T[i][j], x[j], s0);
      s1 = fmaf(T[i][j + 1], x[j + 1], s1);
      s2 = fmaf(T[i][j + 2], x[j + 2], s2);
      s3 = fmaf(T[i][j + 3], x[j + 3], s3);
    }
#pragma unroll
    for (int j = (i / 4) * 4; j < i; ++j) s0 = fmaf(T[i][j], x[j], s0);
    const float a = Y[(size_t)(c0 + i) * D + col] - ((s0 + s1) + (s2 + s3));
    x[i] = a / T[i][i];
    Y[(size_t)(c0 + i) * D + col] = x[i];
  }
  __syncthreads();
}

__device__ void ph_bsolve(float* sm, const float* F, float* Y, int k, int vb) {
  float (*T)[65] = (float(*)[65])sm;
  const int tid = threadIdx.x;
  const int c0 = k * NBK;
  for (int e = tid; e < 4096; e += 256) { const int r = e >> 6, c = e & 63; T[c][r] = F[(size_t)(c0 + r) * D + c0 + c]; }
  __syncthreads();
  const int col = vb * 256 + tid;
  float x[64];
#pragma unroll
  for (int i = 63; i >= 0; --i) {
    float s0 = 0.f, s1 = 0.f, s2 = 0.f, s3 = 0.f;
#pragma unroll
    for (int j = i + 1; j + 3 < 64; j += 4) {
      s0 = fmaf(T[i][j], x[j], s0);
      s1 = fmaf(T[i][j + 1], x[j + 1], s1);
      s2 = fmaf(T[i][j + 2], x[j + 2], s2);
      s3 = fmaf(T[i][j + 3], x[j + 3], s3);
    }
#pragma unroll
    for (int j = i + 1 + (((63 - i) / 4) * 4); j < 64; ++j) s0 = fmaf(T[i][j], x[j], s0);
    const float a = Y[(size_t)(c0 + i) * D + col] - ((s0 + s1) + (s2 + s3));
    x[i] = a;
    Y[(size_t)(c0 + i) * D + col] = a;
  }
  __syncthreads();
}

__device__ void ph_tn(float* sm, const float* F, float* Y, int k, int rlo, int vbx, int vby) {
  const int c0 = k * NBK;
  float (*As)[68] = (float(*)[68])sm;
  float (*Bs)[68] = (float(*)[68])&sm[4352];
  const int tid = threadIdx.x;
  const int cc0 = vbx * 64;
  const int r0 = rlo + vby * 64;
  for (int e = tid; e < 4096; e += 256) {
    const int r = e >> 6, c = e & 63;
    As[r][c] = F[(size_t)(c0 + r) * D + r0 + c];
    Bs[r][c] = Y[(size_t)(c0 + r) * D + cc0 + c];
  }
  __syncthreads();
  float acc[4][4] = {};
  tile_fma(As, Bs, acc, tid & 15, tid >> 4);
  const int tx = tid & 15, ty = tid >> 4;
  for (int i = 0; i < 4; ++i)
    for (int j = 0; j < 4; ++j)
      Y[(size_t)(r0 + ty * 4 + i) * D + cc0 + tx * 4 + j] -= acc[i][j];
  __syncthreads();
}

__device__ void ph_scatter(const float* Y, float* Wm, const int* perm, int add, int vb) {
  const int i = vb >> 2;
  const int c = (vb & 3) * 256 + threadIdx.x;
  const int dst = perm[i];
  const float v = Y[(size_t)i * D + c];
  if (add) Wm[(size_t)dst * D + c] += v;
  else Wm[(size_t)dst * D + c] = v;
}

__device__ void ph_residual(float* sm, const float* Lmat, const float* Wm,
                            const float* CT, float* Y, int vbx, int vby) {
  float (*As)[68] = (float(*)[68])sm;
  float (*Bs)[68] = (float(*)[68])&sm[4352];
  const int tid = threadIdx.x;
  const int cc0 = vbx * 64;
  const int i0 = vby * 64;
  float acc[4][4] = {};
  for (int kb = 0; kb < D; kb += 64) {
    for (int e = tid; e < 4096; e += 256) {
      const int r = e >> 6, c = e & 63;
      As[r][c] = Lmat[(size_t)(kb + r) * D + i0 + c];
      Bs[r][c] = Wm[(size_t)(kb + r) * D + cc0 + c];
    }
    __syncthreads();
    tile_fma(As, Bs, acc, tid & 15, tid >> 4);
    __syncthreads();
  }
  const int tx = tid & 15, ty = tid >> 4;
  for (int i = 0; i < 4; ++i)
    for (int j = 0; j < 4; ++j) {
      const size_t idx = (size_t)(i0 + ty * 4 + i) * D + cc0 + tx * 4 + j;
      Y[idx] = CT[idx] - acc[i][j];
    }
  __syncthreads();
}

__device__ void ph_round(float* sm, const float* yout, const float* Wm, const float* cmat,
                         float* t, float* q, int vbx, int vby) {
  float (*As)[68] = (float(*)[68])sm;
  float (*Bs)[68] = (float(*)[68])&sm[4352];
  const int tid = threadIdx.x;
  const int i0 = vbx * 64;
  const int b0 = vby * 64;
  float acc[4][4] = {};
  for (int kb = 0; kb < D; kb += 64) {
    for (int e = tid; e < 4096; e += 256) {
      const int r = e >> 6, c = e & 63;
      As[c][r] = yout[(size_t)(b0 + r) * D + kb + c];
      Bs[r][c] = Wm[(size_t)(kb + r) * D + i0 + c];
    }
    __syncthreads();
    tile_fma(As, Bs, acc, tid & 15, tid >> 4);
    __syncthreads();
  }
  const int tx = tid & 15, ty = tid >> 4;
  for (int i = 0; i < 4; ++i)
    for (int j = 0; j < 4; ++j) {
      const int b = b0 + ty * 4 + i, col = i0 + tx * 4 + j;
      const float v = yout[(size_t)b * D + col] - XRHOV * acc[i][j] - RHOV * cmat[(size_t)b * D + col];
      t[(size_t)b * D + col] = v;
      q[(size_t)b * D + col] = 0.0f;
    }
  __syncthreads();
}

// ---------------- fused Dykstra iteration: block owns 2 rows, 1 barrier/iter ----------------
// LDS: ts[2][1024] @0, us[2][256] @2048, tile[64][65] @2560, part[4][128] @6720, red[256] @7232
__device__ void ph_dyk(float* sm, float* t, float* q, float* yout,
                       const float* Amat, const float* AAm, const float* bvec,
                       float* err, int slot, int bid) {
  const int tid = threadIdx.x;
  float* ts = sm;
  float* us = sm + 2048;
  float (*tile)[65] = (float(*)[65])(sm + 2560);
  float* part = sm + 6720;
  float* red = sm + 7232;
  const int r0 = bid * 2;
  const int lane = tid & 63, quad = tid >> 6;

  for (int e = tid; e < 2048; e += 256) ts[e] = t[(size_t)r0 * D + e];
  __syncthreads();

  // u = t_rows @ A^T - b  (A: [256][1024] row-major)
  for (int mt = 0; mt < 4; ++mt) {
    const int m0 = mt * 64;
    float a0 = 0.f, a1 = 0.f;
    for (int kt = 0; kt < 16; ++kt) {
      const int k0 = kt * 64;
      for (int e = tid; e < 1024; e += 256) {
        const int r = e >> 4, c = e & 15;
        const float4 v = *(const float4*)&Amat[(size_t)(m0 + r) * D + k0 + c * 4];
        tile[r][c * 4 + 0] = v.x; tile[r][c * 4 + 1] = v.y;
        tile[r][c * 4 + 2] = v.z; tile[r][c * 4 + 3] = v.w;
      }
      __syncthreads();
      const int kb = quad * 16;
#pragma unroll
      for (int kk = 0; kk < 16; ++kk) {
        const float av = tile[lane][kb + kk];
        a0 = fmaf(ts[k0 + kb + kk], av, a0);
        a1 = fmaf(ts[1024 + k0 + kb + kk], av, a1);
      }
      __syncthreads();
    }
    part[quad * 128 + lane] = a0;
    part[quad * 128 + 64 + lane] = a1;
    __syncthreads();
    if (tid < 128) {
      const int row = tid >> 6, l = tid & 63;
      const float s = part[row * 64 + l] + part[128 + row * 64 + l] +
                      part[256 + row * 64 + l] + part[384 + row * 64 + l];
      us[row * 256 + m0 + l] = s - bvec[m0 + l];
    }
    __syncthreads();
  }

  // y = t - us @ AA^T  (AA: [1024][256] row-major), fused elementwise + err
  float nmax = 0.f;
  for (int dt = 0; dt < 16; ++dt) {
    const int d0 = dt * 64;
    float a0 = 0.f, a1 = 0.f;
    for (int mt = 0; mt < 4; ++mt) {
      const int m0 = mt * 64;
      for (int e = tid; e < 1024; e += 256) {
        const int r = e >> 4, c = e & 15;
        const float4 v = *(const float4*)&AAm[(size_t)(d0 + r) * MC + m0 + c * 4];
        tile[r][c * 4 + 0] = v.x; tile[r][c * 4 + 1] = v.y;
        tile[r][c * 4 + 2] = v.z; tile[r][c * 4 + 3] = v.w;
      }
      __syncthreads();
      const int mb = quad * 16;
#pragma unroll
      for (int mm = 0; mm < 16; ++mm) {
        const float av = tile[lane][mb + mm];
        a0 = fmaf(us[m0 + mb + mm], av, a0);
        a1 = fmaf(us[256 + m0 + mb + mm], av, a1);
      }
      __syncthreads();
    }
    part[quad * 128 + lane] = a0;
    part[quad * 128 + 64 + lane] = a1;
    __syncthreads();
    if (tid < 128) {
      const int row = tid >> 6, l = tid & 63;
      const float dot = part[row * 64 + l] + part[128 + row * 64 + l] +
                        part[256 + row * 64 + l] + part[384 + row * 64 + l];
      const int d = d0 + l;
      const size_t idx = (size_t)(r0 + row) * D + d;
      const float tv = ts[row * 1024 + d];
      const float y = tv - dot;
      yout[idx] = y;
      const float qv = q[idx];
      const float yq = y + qv;
      const float xn = fmaxf(yq, 0.f);
      t[idx] = xn + (tv - y);
      q[idx] = yq - xn;
      nmax = fmaxf(nmax, -y);
    }
    __syncthreads();
  }
  red[tid] = nmax;
  __syncthreads();
  for (int s = 128; s > 0; s >>= 1) {
    if (tid < s) red[tid] = fmaxf(red[tid], red[tid + s]);
    __syncthreads();
  }
  if (tid == 0) atomicMax((int*)&err[slot], __float_as_int(red[0]));
  __syncthreads();
}

// ---------------- the megakernel ----------------
__global__ __launch_bounds__(256, 1) void mega(KArgs a) {
  __shared__ alignas(16) float sm[8964];
  const int bid = blockIdx.x;
  const int tid = threadIdx.x;
  unsigned bgen = 0;

  // init t=-rho*c, q=0, perm (arrive/gen/err zeroed by host memset)
  {
    const int gtid = bid * 256 + tid;
    for (int i = gtid; i < BSZ * D; i += GRID * 256) {
      a.t[i] = -RHOV * a.c[i];
      a.q[i] = 0.0f;
    }
    if (gtid < D) a.perm[gtid] = gtid;
  }
  for (int vb = bid; vb < 256; vb += GRID) ph_prep(sm, vb, a.L, a.Lam, a.F, a.Ybuf, a.CT);
  gbar(a.arrive, a.gen, bgen);

  // blocked LU with block-local partial pivoting
  for (int k = 0; k < NPAN; ++k) {
    if (bid == 0) ph_lu_diag(sm, a.F, a.perm, k);
    gbar(a.arrive, a.gen, bgen);
    const int rem = D - (k + 1) * NBK;
    if (rem > 0) {
      const int nvb = (rem + 255) / 256;
      for (int vb = bid; vb < 2 * nvb; vb += GRID) {
        if (vb < nvb) ph_l21(sm, a.F, k, vb);
        else ph_trsm(sm, a.F, k, vb - nvb);
      }
      gbar(a.arrive, a.gen, bgen);
      const int nt = rem / 64;
      for (int vb = bid; vb < nt * nt; vb += GRID) ph_gemm_nn(sm, a.F, k, vb % nt, vb / nt);
      gbar(a.arrive, a.gen, bgen);
    }
  }

  // two solve passes (pass 1 = iterative refinement)
  for (int pass = 0; pass < 2; ++pass) {
    for (int k = 0; k < NPAN; ++k) {
      for (int vb = bid; vb < 4; vb += GRID) ph_fsolve(sm, a.F, a.Ybuf, k, vb);
      gbar(a.arrive, a.gen, bgen);
      const int rem = D - (k + 1) * NBK;
      if (rem > 0) {
        for (int vb = bid; vb < 16 * (rem / 64); vb += GRID)
          ph_tn(sm, a.F, a.Ybuf, k, (k + 1) * NBK, vb & 15, vb >> 4);
        gbar(a.arrive, a.gen, bgen);
      }
    }
    for (int k = NPAN - 1; k >= 0; --k) {
      for (int vb = bid; vb < 4; vb += GRID) ph_bsolve(sm, a.F, a.Ybuf, k, vb);
      gbar(a.arrive, a.gen, bgen);
      if (k > 0) {
        for (int vb = bid; vb < 16 * k; vb += GRID)
          ph_tn(sm, a.F, a.Ybuf, k, 0, vb & 15, vb >> 4);
        gbar(a.arrive, a.gen, bgen);
      }
    }
    for (int vb = bid; vb < 4 * D; vb += GRID) ph_scatter(a.Ybuf, a.Wm, a.perm, pass, vb);
    gbar(a.arrive, a.gen, bgen);
    if (pass == 0) {
      for (int vb = bid; vb < 256; vb += GRID)
        ph_residual(sm, a.L, a.Wm, a.CT, a.Ybuf, vb & 15, vb >> 4);
      gbar(a.arrive, a.gen, bgen);
    }
  }

  // 3 rounds of step + fused Dykstra (1 barrier/iter, uniform early exit)
  for (int r = 0; r < N_ROUNDS; ++r) {
    if (r > 0) {
      for (int vb = bid; vb < 128; vb += GRID)
        ph_round(sm, a.yout, a.Wm, a.c, a.t, a.q, vb & 15, vb >> 4);
      gbar(a.arrive, a.gen, bgen);
    }
    const int base = r * MAXIT;
    for (int it = 0; it < MAXIT; ++it) {
      ph_dyk(sm, a.t, a.q, a.yout, a.A, a.AA, a.b, a.err, base + it, bid);
      gbar(a.arrive, a.gen, bgen);
      const int eb = __hip_atomic_load((int*)&a.err[base + it], __ATOMIC_RELAXED,
                                       __HIP_MEMORY_SCOPE_AGENT);
      if (__int_as_float(eb) < TOLV) break;  // uniform: final after barrier
    }
  }
}

extern "C" void kernel_launch(void* const* d_in, const int* in_sizes, int n_in,
                              void* d_out, int out_size, void* d_ws, size_t ws_size,
                              hipStream_t stream) {
  (void)in_sizes; (void)n_in; (void)out_size; (void)ws_size;
  KArgs a;
  a.c   = (const float*)d_in[0];
  a.A   = (const float*)d_in[1];
  a.b   = (const float*)d_in[2];
  a.AA  = (const float*)d_in[3];
  a.L   = (const float*)d_in[4];
  a.Lam = (const float*)d_in[5];
  a.yout = (float*)d_out;

  // ctrl region (zeroed every call; ws is NOT re-poisoned between replays)
  char* w = (char*)d_ws;
  a.arrive = (unsigned*)w;              // 256 slots, 64B stride = 16384 B
  a.gen    = (unsigned*)(w + 16384);
  a.err    = (float*)(w + 16448);       // 90 slots
  w += 20480;
  a.F    = (float*)w; w += (size_t)D * D * 4;
  a.Ybuf = (float*)w; w += (size_t)D * D * 4;
  a.Wm   = (float*)w; w += (size_t)D * D * 4;
  a.CT   = (float*)w; w += (size_t)D * D * 4;
  a.t    = (float*)w; w += (size_t)BSZ * D * 4;
  a.q    = (float*)w; w += (size_t)BSZ * D * 4;
  a.perm = (int*)w;   w += D * 4;

  hipMemsetAsync(d_ws, 0, 20480, stream);
  mega<<<dim3(GRID), dim3(256), 0, stream>>>(a);
}

// Round 5
// 7888.171 us; speedup vs baseline: 2.1338x; 2.0797x over previous
//
#include <hip/hip_runtime.h>

#define D      1024
#define BSZ    512
#define MC     256
#define NBK    64
#define NPAN   16
#define N_ROUNDS 3
#define MAXIT  30
#define TOLV   0.01f
#define RHOV   3.0f
#define XRHOV  0.5f
#define GRID   256
#define NDYK   128   // blocks doing Dykstra, 4 rows each

// dyk LDS float offsets
#define TS   0
#define QS   4096
#define US   8192
#define PART 9216
#define BS   13312
#define RED  13568
#define ITS  13576
#define SMF  13600

// dyk_iter mode bits
#define DM_HIST 1
#define DM_UPD  2
#define DM_ERR  4
#define DM_OUT  8

struct KArgs {
  const float *c, *A, *b, *AA, *L, *Lam;
  float *yout, *F, *Ybuf, *Wm, *CT;
  float *t, *err, *At, *AAt, *yhist;  // yhist may be null
  int *perm;
  unsigned *arrive, *gen;
};

// ---------------- grid barrier: per-block arrive slots + 8-way gen fan-out ----------------
__device__ __forceinline__ void gbar(unsigned* arrive, unsigned* gen, unsigned& bgen) {
  __syncthreads();
  bgen += 1u;
  const unsigned target = bgen;
  if (threadIdx.x == 0) {
    __builtin_amdgcn_fence(__ATOMIC_RELEASE, "agent");
    __hip_atomic_store(&arrive[blockIdx.x * 16], target, __ATOMIC_RELAXED,
                       __HIP_MEMORY_SCOPE_AGENT);
  }
  if (blockIdx.x == 0) {
    while (__hip_atomic_load(&arrive[threadIdx.x * 16], __ATOMIC_RELAXED,
                             __HIP_MEMORY_SCOPE_AGENT) < target)
      __builtin_amdgcn_s_sleep(2);
    __builtin_amdgcn_fence(__ATOMIC_ACQUIRE, "agent");
    __syncthreads();
    if (threadIdx.x < 8)
      __hip_atomic_store(&gen[threadIdx.x * 16], target, __ATOMIC_RELEASE,
                         __HIP_MEMORY_SCOPE_AGENT);
  }
  if (threadIdx.x == 0) {
    while (__hip_atomic_load(&gen[(blockIdx.x & 7) * 16], __ATOMIC_RELAXED,
                             __HIP_MEMORY_SCOPE_AGENT) < target)
      __builtin_amdgcn_s_sleep(2);
    __builtin_amdgcn_fence(__ATOMIC_ACQUIRE, "agent");
  }
  __syncthreads();
}

// ---------------- shared tile FMA (64x64 tile, 4x4 per thread) ----------------
__device__ __forceinline__ void tile_fma(const float (*As)[68], const float (*Bs)[68],
                                         float acc[4][4], const int tx, const int ty) {
#pragma unroll 8
  for (int kk = 0; kk < 64; ++kk) {
    const float4 a4 = *(const float4*)(&As[kk][ty * 4]);
    const float4 b4 = *(const float4*)(&Bs[kk][tx * 4]);
    const float a0 = a4.x, a1 = a4.y, a2 = a4.z, a3 = a4.w;
    const float b0 = b4.x, b1 = b4.y, b2 = b4.z, b3 = b4.w;
    acc[0][0] = fmaf(a0, b0, acc[0][0]); acc[0][1] = fmaf(a0, b1, acc[0][1]);
    acc[0][2] = fmaf(a0, b2, acc[0][2]); acc[0][3] = fmaf(a0, b3, acc[0][3]);
    acc[1][0] = fmaf(a1, b0, acc[1][0]); acc[1][1] = fmaf(a1, b1, acc[1][1]);
    acc[1][2] = fmaf(a1, b2, acc[1][2]); acc[1][3] = fmaf(a1, b3, acc[1][3]);
    acc[2][0] = fmaf(a2, b0, acc[2][0]); acc[2][1] = fmaf(a2, b1, acc[2][1]);
    acc[2][2] = fmaf(a2, b2, acc[2][2]); acc[2][3] = fmaf(a2, b3, acc[2][3]);
    acc[3][0] = fmaf(a3, b0, acc[3][0]); acc[3][1] = fmaf(a3, b1, acc[3][1]);
    acc[3][2] = fmaf(a3, b2, acc[3][2]); acc[3][3] = fmaf(a3, b3, acc[3][3]);
  }
}

// ---------------- prep / transpose ----------------
__device__ void ph_prep(float* sm, int vb, const float* L, const float* Lam,
                        float* F, float* Ybuf, float* CT) {
  float (*tile)[65] = (float(*)[65])sm;
  const int bi = vb >> 4, bj = vb & 15;
  const int tx = threadIdx.x & 63, ty4 = threadIdx.x >> 6;
  const int i0 = bi * 64, j0 = bj * 64;
  for (int r = ty4; r < 64; r += 4) {
    const float v = L[(size_t)(i0 + r) * D + j0 + tx];
    F[(size_t)(i0 + r) * D + j0 + tx] = v;
    tile[r][tx] = v;
  }
  __syncthreads();
  for (int r = ty4; r < 64; r += 4) {
    const int j = j0 + r;
    const float val = Lam[j] * tile[tx][r];
    Ybuf[(size_t)j * D + i0 + tx] = val;
    CT[(size_t)j * D + i0 + tx] = val;
  }
  __syncthreads();
}

// src[srows][scols] -> dst[scols][srows], tile (tr,tc) of src
__device__ void ph_transpose(float* sm, const float* src, float* dst,
                             int srows, int scols, int tr, int tc) {
  float (*tile)[65] = (float(*)[65])sm;
  const int tx = threadIdx.x & 63, ty = threadIdx.x >> 6;
  for (int r = ty; r < 64; r += 4)
    tile[r][tx] = src[(size_t)(tr * 64 + r) * scols + tc * 64 + tx];
  __syncthreads();
  for (int r = ty; r < 64; r += 4)
    dst[(size_t)(tc * 64 + r) * srows + tr * 64 + tx] = tile[tx][r];
  __syncthreads();
}

// ---------------- LU phases (verified round-1 bodies) ----------------
__device__ void ph_lu_diag(float* sm, float* F, int* perm, int k) {
  float (*blk)[65] = (float(*)[65])sm;
  int* pr_sh = (int*)&sm[8960];
  const int tid = threadIdx.x;
  const int c0 = k * NBK;
  for (int e = tid; e < 4096; e += 256) {
    const int r = e >> 6, c = e & 63;
    blk[r][c] = F[(size_t)(c0 + r) * D + c0 + c];
  }
  __syncthreads();
  for (int j = 0; j < 64; ++j) {
    if (tid < 64) {
      float v = (tid >= j) ? fabsf(blk[tid][j]) : -1.0f;
      int ridx = tid;
      for (int off = 32; off > 0; off >>= 1) {
        const float ov = __shfl_down(v, off);
        const int oi = __shfl_down(ridx, off);
        if (ov > v) { v = ov; ridx = oi; }
      }
      if (tid == 0) *pr_sh = ridx;
    }
    __syncthreads();
    const int pr = *pr_sh;
    if (pr != j) {
      if (tid < 64) { const float a = blk[j][tid], b = blk[pr][tid]; blk[j][tid] = b; blk[pr][tid] = a; }
      if (tid == 0) { const int t = perm[c0 + j]; perm[c0 + j] = perm[c0 + pr]; perm[c0 + pr] = t; }
    }
    __syncthreads();
    if (pr != j) {
      for (int c = tid; c < D; c += 256) {
        if (c >= c0 && c < c0 + 64) continue;
        const float a = F[(size_t)(c0 + j) * D + c], b = F[(size_t)(c0 + pr) * D + c];
        F[(size_t)(c0 + j) * D + c] = b;
        F[(size_t)(c0 + pr) * D + c] = a;
      }
    }
    const float inv = 1.0f / blk[j][j];
    const int r = tid >> 2, l4 = tid & 3;
    if (r > j) {
      const float lval = blk[r][j] * inv;
      if (l4 == 0) blk[r][j] = lval;
      for (int c = j + 1 + l4; c < 64; c += 4)
        blk[r][c] = fmaf(-lval, blk[j][c], blk[r][c]);
    }
    __syncthreads();
  }
  for (int e = tid; e < 4096; e += 256) {
    const int r = e >> 6, c = e & 63;
    F[(size_t)(c0 + r) * D + c0 + c] = blk[r][c];
  }
  __syncthreads();
}

__device__ void ph_l21(float* sm, float* F, int k, int vb) {
  const int c0 = k * NBK;
  const int row0 = c0 + NBK;
  const int nrows = D - row0;
  float (*U)[65] = (float(*)[65])sm;
  const int tid = threadIdx.x;
  for (int e = tid; e < 4096; e += 256) { const int r = e >> 6, c = e & 63; U[r][c] = F[(size_t)(c0 + r) * D + c0 + c]; }
  __syncthreads();
  const int r = vb * 256 + tid;
  if (r >= nrows) return;
  float* Arow = &F[(size_t)(row0 + r) * D + c0];
  float x[64];
#pragma unroll
  for (int jj = 0; jj < 64; ++jj) {
    float s0 = 0.f, s1 = 0.f, s2 = 0.f, s3 = 0.f;
#pragma unroll
    for (int i = 0; i + 3 < jj; i += 4) {
      s0 = fmaf(x[i], U[i][jj], s0);
      s1 = fmaf(x[i + 1], U[i + 1][jj], s1);
      s2 = fmaf(x[i + 2], U[i + 2][jj], s2);
      s3 = fmaf(x[i + 3], U[i + 3][jj], s3);
    }
#pragma unroll
    for (int i = (jj / 4) * 4; i < jj; ++i) s0 = fmaf(x[i], U[i][jj], s0);
    const float a = Arow[jj] - ((s0 + s1) + (s2 + s3));
    x[jj] = a / U[jj][jj];
    Arow[jj] = x[jj];
  }
}

__device__ void ph_trsm(float* sm, float* F, int k, int vb) {
  const int c0 = k * NBK;
  const int colstart = c0 + NBK;
  const int ncols = D - colstart;
  float (*Lw)[65] = (float(*)[65])sm;
  const int tid = threadIdx.x;
  for (int e = tid; e < 4096; e += 256) { const int r = e >> 6, c = e & 63; Lw[r][c] = F[(size_t)(c0 + r) * D + c0 + c]; }
  __syncthreads();
  const int cidx = vb * 256 + tid;
  if (cidx >= ncols) return;
  const int col = colstart + cidx;
  float x[64];
#pragma unroll
  for (int i = 0; i < 64; ++i) {
    float s0 = 0.f, s1 = 0.f, s2 = 0.f, s3 = 0.f;
#pragma unroll
    for (int j = 0; j + 3 < i; j += 4) {
      s0 = fmaf(Lw[i][j], x[j], s0);
      s1 = fmaf(Lw[i][j + 1], x[j + 1], s1);
      s2 = fmaf(Lw[i][j + 2], x[j + 2], s2);
      s3 = fmaf(Lw[i][j + 3], x[j + 3], s3);
    }
#pragma unroll
    for (int j = (i / 4) * 4; j < i; ++j) s0 = fmaf(Lw[i][j], x[j], s0);
    const float a = F[(size_t)(c0 + i) * D + col] - ((s0 + s1) + (s2 + s3));
    x[i] = a;
    F[(size_t)(c0 + i) * D + col] = a;
  }
}

__device__ void ph_gemm_nn(float* sm, float* F, int k, int vbx, int vby) {
  const int c0 = k * NBK;
  const int o = c0 + NBK;
  float (*As)[68] = (float(*)[68])sm;
  float (*Bs)[68] = (float(*)[68])&sm[4352];
  const int tid = threadIdx.x;
  const int cc0 = o + vbx * 64;
  const int r0 = o + vby * 64;
  for (int e = tid; e < 4096; e += 256) {
    const int r = e >> 6, c = e & 63;
    As[c][r] = F[(size_t)(r0 + r) * D + c0 + c];
    Bs[r][c] = F[(size_t)(c0 + r) * D + cc0 + c];
  }
  __syncthreads();
  float acc[4][4] = {};
  tile_fma(As, Bs, acc, tid & 15, tid >> 4);
  const int tx = tid & 15, ty = tid >> 4;
  for (int i = 0; i < 4; ++i)
    for (int j = 0; j < 4; ++j)
      F[(size_t)(r0 + ty * 4 + i) * D + cc0 + tx * 4 + j] -= acc[i][j];
  __syncthreads();
}

__device__ void ph_fsolve(float* sm, const float* F, float* Y, int k, int vb) {
  float (*T)[65] = (float(*)[65])sm;
  const int tid = threadIdx.x;
  const int c0 = k * NBK;
  for (int e = tid; e < 4096; e += 256) { const int r = e >> 6, c = e & 63; T[c][r] = F[(size_t)(c0 + r) * D + c0 + c]; }
  __syncthreads();
  const int col = vb * 256 + tid;
  float x[64];
#pragma unroll
  for (int i = 0; i < 64; ++i) {
    float s0 = 0.f, s1 = 0.f, s2 = 0.f, s3 = 0.f;
#pragma unroll
    for (int j = 0; j + 3 < i; j += 4) {
      s0 = fmaf(T[i][j], x[j], s0);
      s1 = fmaf(T[i][j + 1], x[j + 1], s1);
      s2 = fmaf(T[i][j + 2], x[j + 2], s2);
      s3 = fmaf(T[i][j + 3], x[j + 3], s3);
    }
#pragma unroll
    for (int j = (i / 4) * 4; j < i; ++j) s0 = fmaf(T[i][j], x[j], s0);
    const float a = Y[(size_t)(c0 + i) * D + col] - ((s0 + s1) + (s2 + s3));
    x[i] = a / T[i][i];
    Y[(size_t)(c0 + i) * D + col] = x[i];
  }
  __syncthreads();
}

__device__ void ph_bsolve(float* sm, const float* F, float* Y, int k, int vb) {
  float (*T)[65] = (float(*)[65])sm;
  const int tid = threadIdx.x;
  const int c0 = k * NBK;
  for (int e = tid; e < 4096; e += 256) { const int r = e >> 6, c = e & 63; T[c][r] = F[(size_t)(c0 + r) * D + c0 + c]; }
  __syncthreads();
  const int col = vb * 256 + tid;
  float x[64];
#pragma unroll
  for (int i = 63; i >= 0; --i) {
    float s0 = 0.f, s1 = 0.f, s2 = 0.f, s3 = 0.f;
#pragma unroll
    for (int j = i + 1; j + 3 < 64; j += 4) {
      s0 = fmaf(T[i][j], x[j], s0);
      s1 = fmaf(T[i][j + 1], x[j + 1], s1);
      s2 = fmaf(T[i][j + 2], x[j + 2], s2);
      s3 = fmaf(T[i][j + 3], x[j + 3], s3);
    }
#pragma unroll
    for (int j = i + 1 + (((63 - i) / 4) * 4); j < 64; ++j) s0 = fmaf(T[i][j], x[j], s0);
    const float a = Y[(size_t)(c0 + i) * D + col] - ((s0 + s1) + (s2 + s3));
    x[i] = a;
    Y[(size_t)(c0 + i) * D + col] = a;
  }
  __syncthreads();
}

__device__ void ph_tn(float* sm, const float* F, float* Y, int k, int rlo, int vbx, int vby) {
  const int c0 = k * NBK;
  float (*As)[68] = (float(*)[68])sm;
  float (*Bs)[68] = (float(*)[68])&sm[4352];
  const int tid = threadIdx.x;
  const int cc0 = vbx * 64;
  const int r0 = rlo + vby * 64;
  for (int e = tid; e < 4096; e += 256) {
    const int r = e >> 6, c = e & 63;
    As[r][c] = F[(size_t)(c0 + r) * D + r0 + c];
    Bs[r][c] = Y[(size_t)(c0 + r) * D + cc0 + c];
  }
  __syncthreads();
  float acc[4][4] = {};
  tile_fma(As, Bs, acc, tid & 15, tid >> 4);
  const int tx = tid & 15, ty = tid >> 4;
  for (int i = 0; i < 4; ++i)
    for (int j = 0; j < 4; ++j)
      Y[(size_t)(r0 + ty * 4 + i) * D + cc0 + tx * 4 + j] -= acc[i][j];
  __syncthreads();
}

__device__ void ph_scatter(const float* Y, float* Wm, const int* perm, int add, int vb) {
  const int i = vb >> 2;
  const int c = (vb & 3) * 256 + threadIdx.x;
  const int dst = perm[i];
  const float v = Y[(size_t)i * D + c];
  if (add) Wm[(size_t)dst * D + c] += v;
  else Wm[(size_t)dst * D + c] = v;
}

__device__ void ph_residual(float* sm, const float* Lmat, const float* Wm,
                            const float* CT, float* Y, int vbx, int vby) {
  float (*As)[68] = (float(*)[68])sm;
  float (*Bs)[68] = (float(*)[68])&sm[4352];
  const int tid = threadIdx.x;
  const int cc0 = vbx * 64;
  const int i0 = vby * 64;
  float acc[4][4] = {};
  for (int kb = 0; kb < D; kb += 64) {
    for (int e = tid; e < 4096; e += 256) {
      const int r = e >> 6, c = e & 63;
      As[r][c] = Lmat[(size_t)(kb + r) * D + i0 + c];
      Bs[r][c] = Wm[(size_t)(kb + r) * D + cc0 + c];
    }
    __syncthreads();
    tile_fma(As, Bs, acc, tid & 15, tid >> 4);
    __syncthreads();
  }
  const int tx = tid & 15, ty = tid >> 4;
  for (int i = 0; i < 4; ++i)
    for (int j = 0; j < 4; ++j) {
      const size_t idx = (size_t)(i0 + ty * 4 + i) * D + cc0 + tx * 4 + j;
      Y[idx] = CT[idx] - acc[i][j];
    }
  __syncthreads();
}

__device__ void ph_round(float* sm, const float* yout, const float* Wm, const float* cmat,
                         float* t, int vbx, int vby) {
  float (*As)[68] = (float(*)[68])sm;
  float (*Bs)[68] = (float(*)[68])&sm[4352];
  const int tid = threadIdx.x;
  const int i0 = vbx * 64;
  const int b0 = vby * 64;
  float acc[4][4] = {};
  for (int kb = 0; kb < D; kb += 64) {
    for (int e = tid; e < 4096; e += 256) {
      const int r = e >> 6, c = e & 63;
      As[c][r] = yout[(size_t)(b0 + r) * D + kb + c];
      Bs[r][c] = Wm[(size_t)(kb + r) * D + i0 + c];
    }
    __syncthreads();
    tile_fma(As, Bs, acc, tid & 15, tid >> 4);
    __syncthreads();
  }
  const int tx = tid & 15, ty = tid >> 4;
  for (int i = 0; i < 4; ++i)
    for (int j = 0; j < 4; ++j) {
      const int b = b0 + ty * 4 + i, col = i0 + tx * 4 + j;
      const float v = yout[(size_t)b * D + col] - XRHOV * acc[i][j] - RHOV * cmat[(size_t)b * D + col];
      t[(size_t)b * D + col] = v;
    }
  __syncthreads();
}

// ---------------- block-local Dykstra ----------------
__device__ void dyk_state_init(float* sm, const KArgs& a, int r0) {
  float4* ts4 = (float4*)(sm + TS);
  float4* qs4 = (float4*)(sm + QS);
  const float4* t4 = (const float4*)(a.t + (size_t)r0 * D);
  for (int e = threadIdx.x; e < 1024; e += 256) {
    ts4[e] = t4[e];
    qs4[e] = make_float4(0.f, 0.f, 0.f, 0.f);
  }
  if (threadIdx.x < 256) sm[BS + threadIdx.x] = a.b[threadIdx.x];
  __syncthreads();
}

template <int MODE>
__device__ void dyk_iter(float* sm, const KArgs& a, int r0, int it, int base) {
  const int tid = threadIdx.x;
  float* ts = sm + TS;
  float* qs = sm + QS;
  float* us = sm + US;
  float* part = sm + PART;

  // ---- u-phase: part[ks][r][m] = sum over k-quarter of ts[r][k]*At[k][m]
  const int m4 = tid & 63, ks = tid >> 6;
  const float* AtB = a.At + (size_t)ks * 256 * MC + m4 * 4;
  float4 ua[4];
#pragma unroll
  for (int r = 0; r < 4; ++r) ua[r] = make_float4(0.f, 0.f, 0.f, 0.f);
  const int kb = ks * 256;
#pragma unroll 2
  for (int k4 = 0; k4 < 64; ++k4) {
    float t0[4], t1[4], t2[4], t3[4];
    *(float4*)t0 = *(const float4*)&ts[kb + k4 * 4];
    *(float4*)t1 = *(const float4*)&ts[1024 + kb + k4 * 4];
    *(float4*)t2 = *(const float4*)&ts[2048 + kb + k4 * 4];
    *(float4*)t3 = *(const float4*)&ts[3072 + kb + k4 * 4];
#pragma unroll
    for (int j = 0; j < 4; ++j) {
      const float4 av = *(const float4*)(AtB + (size_t)(k4 * 4 + j) * MC);
      ua[0].x = fmaf(t0[j], av.x, ua[0].x); ua[0].y = fmaf(t0[j], av.y, ua[0].y);
      ua[0].z = fmaf(t0[j], av.z, ua[0].z); ua[0].w = fmaf(t0[j], av.w, ua[0].w);
      ua[1].x = fmaf(t1[j], av.x, ua[1].x); ua[1].y = fmaf(t1[j], av.y, ua[1].y);
      ua[1].z = fmaf(t1[j], av.z, ua[1].z); ua[1].w = fmaf(t1[j], av.w, ua[1].w);
      ua[2].x = fmaf(t2[j], av.x, ua[2].x); ua[2].y = fmaf(t2[j], av.y, ua[2].y);
      ua[2].z = fmaf(t2[j], av.z, ua[2].z); ua[2].w = fmaf(t2[j], av.w, ua[2].w);
      ua[3].x = fmaf(t3[j], av.x, ua[3].x); ua[3].y = fmaf(t3[j], av.y, ua[3].y);
      ua[3].z = fmaf(t3[j], av.z, ua[3].z); ua[3].w = fmaf(t3[j], av.w, ua[3].w);
    }
  }
#pragma unroll
  for (int r = 0; r < 4; ++r) ((float4*)part)[(ks * 4 + r) * 64 + m4] = ua[r];
  __syncthreads();

  // ---- reduce partials: us[r][m] = sum_ks part - b[m]
  {
    const int m = tid;
#pragma unroll
    for (int r = 0; r < 4; ++r)
      us[r * 256 + m] = part[r * 256 + m] + part[1024 + r * 256 + m] +
                        part[2048 + r * 256 + m] + part[3072 + r * 256 + m] - sm[BS + m];
  }
  __syncthreads();

  // ---- y-phase: y[r][d] = ts[r][d] - sum_m us[r][m]*AAt[m][d]; d-group = tid*4
  float4 ya[4];
#pragma unroll
  for (int r = 0; r < 4; ++r) ya[r] = make_float4(0.f, 0.f, 0.f, 0.f);
  const float4* AAB = (const float4*)a.AAt;
#pragma unroll 2
  for (int mi = 0; mi < 64; ++mi) {
    float u0[4], u1[4], u2[4], u3[4];
    *(float4*)u0 = *(const float4*)&us[mi * 4];
    *(float4*)u1 = *(const float4*)&us[256 + mi * 4];
    *(float4*)u2 = *(const float4*)&us[512 + mi * 4];
    *(float4*)u3 = *(const float4*)&us[768 + mi * 4];
#pragma unroll
    for (int j = 0; j < 4; ++j) {
      const float4 w = AAB[(size_t)(mi * 4 + j) * (D / 4) + tid];
      ya[0].x = fmaf(u0[j], w.x, ya[0].x); ya[0].y = fmaf(u0[j], w.y, ya[0].y);
      ya[0].z = fmaf(u0[j], w.z, ya[0].z); ya[0].w = fmaf(u0[j], w.w, ya[0].w);
      ya[1].x = fmaf(u1[j], w.x, ya[1].x); ya[1].y = fmaf(u1[j], w.y, ya[1].y);
      ya[1].z = fmaf(u1[j], w.z, ya[1].z); ya[1].w = fmaf(u1[j], w.w, ya[1].w);
      ya[2].x = fmaf(u2[j], w.x, ya[2].x); ya[2].y = fmaf(u2[j], w.y, ya[2].y);
      ya[2].z = fmaf(u2[j], w.z, ya[2].z); ya[2].w = fmaf(u2[j], w.w, ya[2].w);
      ya[3].x = fmaf(u3[j], w.x, ya[3].x); ya[3].y = fmaf(u3[j], w.y, ya[3].y);
      ya[3].z = fmaf(u3[j], w.z, ya[3].z); ya[3].w = fmaf(u3[j], w.w, ya[3].w);
    }
  }

  float nmax = 0.f;
#pragma unroll
  for (int r = 0; r < 4; ++r) {
    const float4 tv = *(const float4*)&ts[r * 1024 + tid * 4];
    float4 y;
    y.x = tv.x - ya[r].x; y.y = tv.y - ya[r].y;
    y.z = tv.z - ya[r].z; y.w = tv.w - ya[r].w;
    if (MODE & DM_HIST)
      ((float4*)a.yhist)[((size_t)it * BSZ + r0 + r) * (D / 4) + tid] = y;
    if (MODE & DM_OUT)
      ((float4*)a.yout)[(size_t)(r0 + r) * (D / 4) + tid] = y;
    if (MODE & DM_UPD) {
      const float4 qv = *(const float4*)&qs[r * 1024 + tid * 4];
      float4 tn, qn;
      { const float yq = y.x + qv.x, xn = fmaxf(yq, 0.f); tn.x = xn + (tv.x - y.x); qn.x = yq - xn; }
      { const float yq = y.y + qv.y, xn = fmaxf(yq, 0.f); tn.y = xn + (tv.y - y.y); qn.y = yq - xn; }
      { const float yq = y.z + qv.z, xn = fmaxf(yq, 0.f); tn.z = xn + (tv.z - y.z); qn.z = yq - xn; }
      { const float yq = y.w + qv.w, xn = fmaxf(yq, 0.f); tn.w = xn + (tv.w - y.w); qn.w = yq - xn; }
      *(float4*)&ts[r * 1024 + tid * 4] = tn;
      *(float4*)&qs[r * 1024 + tid * 4] = qn;
    }
    if (MODE & DM_ERR) {
      nmax = fmaxf(nmax, -y.x); nmax = fmaxf(nmax, -y.y);
      nmax = fmaxf(nmax, -y.z); nmax = fmaxf(nmax, -y.w);
    }
  }
  if (MODE & DM_ERR) {
#pragma unroll
    for (int off = 32; off > 0; off >>= 1) nmax = fmaxf(nmax, __shfl_down(nmax, off));
    if ((tid & 63) == 0) sm[RED + (tid >> 6)] = nmax;
  }
  __syncthreads();
  if ((MODE & DM_ERR) && tid == 0) {
    const float m = fmaxf(fmaxf(sm[RED], sm[RED + 1]), fmaxf(sm[RED + 2], sm[RED + 3]));
    atomicMax((int*)&a.err[base + it], __float_as_int(m));
  }
}

__device__ int scan_itstar(float* sm, const float* err, int base) {
  int* its = (int*)&sm[ITS];
  if (threadIdx.x < 64) {
    int conv = 0;
    if (threadIdx.x < MAXIT) {
      const int bits = __hip_atomic_load((const int*)&err[base + threadIdx.x],
                                         __ATOMIC_RELAXED, __HIP_MEMORY_SCOPE_AGENT);
      conv = (__int_as_float(bits) < TOLV) ? 1 : 0;
    }
    const unsigned long long msk = __ballot(conv);
    if (threadIdx.x == 0)
      its[0] = msk ? (int)__builtin_ctzll(msk) : (MAXIT - 1);
  }
  __syncthreads();
  return its[0];
}

// ---------------- the megakernel ----------------
__global__ __launch_bounds__(256, 1) void mega(KArgs a) {
  __shared__ alignas(16) float sm[SMF];
  const int bid = blockIdx.x;
  const int tid = threadIdx.x;
  unsigned bgen = 0;

  // phase 0: init t=-rho*c, perm; prep F/CT/Ybuf; build At/AAt transposes
  {
    const int gtid = bid * 256 + tid;
    for (int i = gtid; i < BSZ * D; i += GRID * 256) a.t[i] = -RHOV * a.c[i];
    if (gtid < D) a.perm[gtid] = gtid;
  }
  for (int vb = bid; vb < 384; vb += GRID) {
    if (vb < 256) ph_prep(sm, vb, a.L, a.Lam, a.F, a.Ybuf, a.CT);
    else if (vb < 320) { const int tt = vb - 256; ph_transpose(sm, a.A, a.At, MC, D, tt & 3, tt >> 2); }
    else { const int tt = vb - 320; ph_transpose(sm, a.AA, a.AAt, D, MC, tt & 15, tt >> 4); }
  }
  gbar(a.arrive, a.gen, bgen);

  // blocked LU with block-local partial pivoting
  for (int k = 0; k < NPAN; ++k) {
    if (bid == 0) ph_lu_diag(sm, a.F, a.perm, k);
    gbar(a.arrive, a.gen, bgen);
    const int rem = D - (k + 1) * NBK;
    if (rem > 0) {
      const int nvb = (rem + 255) / 256;
      for (int vb = bid; vb < 2 * nvb; vb += GRID) {
        if (vb < nvb) ph_l21(sm, a.F, k, vb);
        else ph_trsm(sm, a.F, k, vb - nvb);
      }
      gbar(a.arrive, a.gen, bgen);
      const int nt = rem / 64;
      for (int vb = bid; vb < nt * nt; vb += GRID) ph_gemm_nn(sm, a.F, k, vb % nt, vb / nt);
      gbar(a.arrive, a.gen, bgen);
    }
  }

  // two solve passes (pass 1 = iterative refinement)
  for (int pass = 0; pass < 2; ++pass) {
    for (int k = 0; k < NPAN; ++k) {
      for (int vb = bid; vb < 4; vb += GRID) ph_fsolve(sm, a.F, a.Ybuf, k, vb);
      gbar(a.arrive, a.gen, bgen);
      const int rem = D - (k + 1) * NBK;
      if (rem > 0) {
        for (int vb = bid; vb < 16 * (rem / 64); vb += GRID)
          ph_tn(sm, a.F, a.Ybuf, k, (k + 1) * NBK, vb & 15, vb >> 4);
        gbar(a.arrive, a.gen, bgen);
      }
    }
    for (int k = NPAN - 1; k >= 0; --k) {
      for (int vb = bid; vb < 4; vb += GRID) ph_bsolve(sm, a.F, a.Ybuf, k, vb);
      gbar(a.arrive, a.gen, bgen);
      if (k > 0) {
        for (int vb = bid; vb < 16 * k; vb += GRID)
          ph_tn(sm, a.F, a.Ybuf, k, 0, vb & 15, vb >> 4);
        gbar(a.arrive, a.gen, bgen);
      }
    }
    for (int vb = bid; vb < 4 * D; vb += GRID) ph_scatter(a.Ybuf, a.Wm, a.perm, pass, vb);
    gbar(a.arrive, a.gen, bgen);
    if (pass == 0) {
      for (int vb = bid; vb < 256; vb += GRID)
        ph_residual(sm, a.L, a.Wm, a.CT, a.Ybuf, vb & 15, vb >> 4);
      gbar(a.arrive, a.gen, bgen);
    }
  }

  // 3 rounds: step + block-local Dykstra (barrier-free iterations) + freeze via it*
  const int hist = (a.yhist != nullptr);
  for (int r = 0; r < N_ROUNDS; ++r) {
    if (r > 0) {
      for (int vb = bid; vb < 128; vb += GRID)
        ph_round(sm, a.yout, a.Wm, a.c, a.t, vb & 15, vb >> 4);
      gbar(a.arrive, a.gen, bgen);
    }
    const int base = r * MAXIT;
    if (bid < NDYK) {
      const int r0 = bid * 4;
      dyk_state_init(sm, a, r0);
      if (hist) {
        for (int it = 0; it < MAXIT; ++it)
          dyk_iter<DM_HIST | DM_UPD | DM_ERR>(sm, a, r0, it, base);
      } else {
        for (int it = 0; it < MAXIT; ++it)
          dyk_iter<DM_UPD | DM_ERR>(sm, a, r0, it, base);
      }
    }
    gbar(a.arrive, a.gen, bgen);
    if (bid < NDYK) {
      const int r0 = bid * 4;
      const int itstar = scan_itstar(sm, a.err, base);
      if (hist) {
        const float4* src = (const float4*)(a.yhist + (size_t)itstar * BSZ * D + (size_t)r0 * D);
        float4* dst = (float4*)(a.yout + (size_t)r0 * D);
        for (int e = tid; e < 1024; e += 256) dst[e] = src[e];
      } else {
        dyk_state_init(sm, a, r0);
        for (int it = 0; it < itstar; ++it)
          dyk_iter<DM_UPD>(sm, a, r0, it, base);
        dyk_iter<DM_OUT>(sm, a, r0, itstar, base);
      }
    }
    gbar(a.arrive, a.gen, bgen);
  }
}

extern "C" void kernel_launch(void* const* d_in, const int* in_sizes, int n_in,
                              void* d_out, int out_size, void* d_ws, size_t ws_size,
                              hipStream_t stream) {
  (void)in_sizes; (void)n_in; (void)out_size;
  KArgs a;
  a.c   = (const float*)d_in[0];
  a.A   = (const float*)d_in[1];
  a.b   = (const float*)d_in[2];
  a.AA  = (const float*)d_in[3];
  a.L   = (const float*)d_in[4];
  a.Lam = (const float*)d_in[5];
  a.yout = (float*)d_out;

  // ctrl region (zeroed every call; ws is NOT re-poisoned between replays)
  char* w = (char*)d_ws;
  a.arrive = (unsigned*)w;              // 256 x 64B
  a.gen    = (unsigned*)(w + 16384);    // 8 x 64B
  a.err    = (float*)(w + 16896);       // 90 slots
  w += 20480;
  a.F    = (float*)w; w += (size_t)D * D * 4;
  a.Ybuf = (float*)w; w += (size_t)D * D * 4;
  a.Wm   = (float*)w; w += (size_t)D * D * 4;
  a.CT   = (float*)w; w += (size_t)D * D * 4;
  a.t    = (float*)w; w += (size_t)BSZ * D * 4;
  a.At   = (float*)w; w += (size_t)D * MC * 4;
  a.AAt  = (float*)w; w += (size_t)MC * D * 4;
  a.perm = (int*)w;   w += (size_t)D * 4;

  const size_t used = (size_t)(w - (char*)d_ws);
  const size_t hist_bytes = (size_t)MAXIT * BSZ * D * 4;  // ~63 MB
  a.yhist = (ws_size >= used + hist_bytes) ? (float*)w : nullptr;

  hipMemsetAsync(d_ws, 0, 20480, stream);
  mega<<<dim3(GRID), dim3(256), 0, stream>>>(a);
}

// Round 6
// 6718.153 us; speedup vs baseline: 2.5054x; 1.1742x over previous
//
#include <hip/hip_runtime.h>

#define D      1024
#define BSZ    512
#define MC     256
#define NBK    64
#define NPAN   16
#define N_ROUNDS 3
#define MAXIT  30
#define TOLV   0.01f
#define RHOV   3.0f
#define XRHOV  0.5f
#define GRID   256
#define NGA    128   // group A: Dykstra blocks (4 rows each)
#define NGB    128   // group B: LU/solve blocks

// dyk LDS float offsets
#define TS   0
#define QS   4096
#define US   8192
#define PART 9216
#define BS   13312
#define RED  13568
#define SMF  13600

struct KArgs {
  const float *c, *A, *b, *AA, *L, *Lam;
  float *yout, *F, *Ybuf, *Wm;
  float *t, *err, *At, *AAt;
  int *perm;
  unsigned *slotsF, *slotsG;  // full-grid / per-group barrier slots (64B stride)
};

// ---------------- flat grid barrier: own-slot store + parallel poll ----------------
__device__ __forceinline__ void fbar(unsigned* slots, int lid, int count, unsigned target) {
  __syncthreads();
  if (threadIdx.x == 0) {
    __builtin_amdgcn_fence(__ATOMIC_RELEASE, "agent");
    __hip_atomic_store(&slots[lid * 16], target, __ATOMIC_RELAXED, __HIP_MEMORY_SCOPE_AGENT);
  }
  for (int i = threadIdx.x; i < count; i += 256)
    while (__hip_atomic_load(&slots[i * 16], __ATOMIC_RELAXED, __HIP_MEMORY_SCOPE_AGENT) < target)
      __builtin_amdgcn_s_sleep(1);
  __builtin_amdgcn_fence(__ATOMIC_ACQUIRE, "agent");
  __syncthreads();
}

// ---------------- shared tile FMA (64x64 tile, 4x4 per thread) ----------------
__device__ __forceinline__ void tile_fma(const float (*As)[68], const float (*Bs)[68],
                                         float acc[4][4], const int tx, const int ty) {
#pragma unroll 8
  for (int kk = 0; kk < 64; ++kk) {
    const float4 a4 = *(const float4*)(&As[kk][ty * 4]);
    const float4 b4 = *(const float4*)(&Bs[kk][tx * 4]);
    const float a0 = a4.x, a1 = a4.y, a2 = a4.z, a3 = a4.w;
    const float b0 = b4.x, b1 = b4.y, b2 = b4.z, b3 = b4.w;
    acc[0][0] = fmaf(a0, b0, acc[0][0]); acc[0][1] = fmaf(a0, b1, acc[0][1]);
    acc[0][2] = fmaf(a0, b2, acc[0][2]); acc[0][3] = fmaf(a0, b3, acc[0][3]);
    acc[1][0] = fmaf(a1, b0, acc[1][0]); acc[1][1] = fmaf(a1, b1, acc[1][1]);
    acc[1][2] = fmaf(a1, b2, acc[1][2]); acc[1][3] = fmaf(a1, b3, acc[1][3]);
    acc[2][0] = fmaf(a2, b0, acc[2][0]); acc[2][1] = fmaf(a2, b1, acc[2][1]);
    acc[2][2] = fmaf(a2, b2, acc[2][2]); acc[2][3] = fmaf(a2, b3, acc[2][3]);
    acc[3][0] = fmaf(a3, b0, acc[3][0]); acc[3][1] = fmaf(a3, b1, acc[3][1]);
    acc[3][2] = fmaf(a3, b2, acc[3][2]); acc[3][3] = fmaf(a3, b3, acc[3][3]);
  }
}

// ---------------- prep / transpose ----------------
__device__ void ph_prep(float* sm, int vb, const float* L, const float* Lam,
                        float* F, float* Ybuf) {
  float (*tile)[65] = (float(*)[65])sm;
  const int bi = vb >> 4, bj = vb & 15;
  const int tx = threadIdx.x & 63, ty4 = threadIdx.x >> 6;
  const int i0 = bi * 64, j0 = bj * 64;
  for (int r = ty4; r < 64; r += 4) {
    const float v = L[(size_t)(i0 + r) * D + j0 + tx];
    F[(size_t)(i0 + r) * D + j0 + tx] = v;
    tile[r][tx] = v;
  }
  __syncthreads();
  for (int r = ty4; r < 64; r += 4) {
    const int j = j0 + r;
    Ybuf[(size_t)j * D + i0 + tx] = Lam[j] * tile[tx][r];
  }
  __syncthreads();
}

__device__ void ph_transpose(float* sm, const float* src, float* dst,
                             int srows, int scols, int tr, int tc) {
  float (*tile)[65] = (float(*)[65])sm;
  const int tx = threadIdx.x & 63, ty = threadIdx.x >> 6;
  for (int r = ty; r < 64; r += 4)
    tile[r][tx] = src[(size_t)(tr * 64 + r) * scols + tc * 64 + tx];
  __syncthreads();
  for (int r = ty; r < 64; r += 4)
    dst[(size_t)(tc * 64 + r) * srows + tr * 64 + tx] = tile[tx][r];
  __syncthreads();
}

// ---------------- LU phases (verified bodies) ----------------
__device__ void ph_lu_diag(float* sm, float* F, int* perm, int k) {
  float (*blk)[65] = (float(*)[65])sm;
  int* pr_sh = (int*)&sm[8960];
  const int tid = threadIdx.x;
  const int c0 = k * NBK;
  for (int e = tid; e < 4096; e += 256) {
    const int r = e >> 6, c = e & 63;
    blk[r][c] = F[(size_t)(c0 + r) * D + c0 + c];
  }
  __syncthreads();
  for (int j = 0; j < 64; ++j) {
    if (tid < 64) {
      float v = (tid >= j) ? fabsf(blk[tid][j]) : -1.0f;
      int ridx = tid;
      for (int off = 32; off > 0; off >>= 1) {
        const float ov = __shfl_down(v, off);
        const int oi = __shfl_down(ridx, off);
        if (ov > v) { v = ov; ridx = oi; }
      }
      if (tid == 0) *pr_sh = ridx;
    }
    __syncthreads();
    const int pr = *pr_sh;
    if (pr != j) {
      if (tid < 64) { const float a = blk[j][tid], b = blk[pr][tid]; blk[j][tid] = b; blk[pr][tid] = a; }
      if (tid == 0) { const int t = perm[c0 + j]; perm[c0 + j] = perm[c0 + pr]; perm[c0 + pr] = t; }
    }
    __syncthreads();
    if (pr != j) {
      for (int c = tid; c < D; c += 256) {
        if (c >= c0 && c < c0 + 64) continue;
        const float a = F[(size_t)(c0 + j) * D + c], b = F[(size_t)(c0 + pr) * D + c];
        F[(size_t)(c0 + j) * D + c] = b;
        F[(size_t)(c0 + pr) * D + c] = a;
      }
    }
    const float inv = 1.0f / blk[j][j];
    const int r = tid >> 2, l4 = tid & 3;
    if (r > j) {
      const float lval = blk[r][j] * inv;
      if (l4 == 0) blk[r][j] = lval;
      for (int c = j + 1 + l4; c < 64; c += 4)
        blk[r][c] = fmaf(-lval, blk[j][c], blk[r][c]);
    }
    __syncthreads();
  }
  for (int e = tid; e < 4096; e += 256) {
    const int r = e >> 6, c = e & 63;
    F[(size_t)(c0 + r) * D + c0 + c] = blk[r][c];
  }
  __syncthreads();
}

__device__ void ph_l21(float* sm, float* F, int k, int vb) {
  const int c0 = k * NBK;
  const int row0 = c0 + NBK;
  const int nrows = D - row0;
  float (*U)[65] = (float(*)[65])sm;
  const int tid = threadIdx.x;
  for (int e = tid; e < 4096; e += 256) { const int r = e >> 6, c = e & 63; U[r][c] = F[(size_t)(c0 + r) * D + c0 + c]; }
  __syncthreads();
  const int r = vb * 256 + tid;
  if (r >= nrows) return;
  float* Arow = &F[(size_t)(row0 + r) * D + c0];
  float x[64];
#pragma unroll
  for (int jj = 0; jj < 64; ++jj) {
    float s0 = 0.f, s1 = 0.f, s2 = 0.f, s3 = 0.f;
#pragma unroll
    for (int i = 0; i + 3 < jj; i += 4) {
      s0 = fmaf(x[i], U[i][jj], s0);
      s1 = fmaf(x[i + 1], U[i + 1][jj], s1);
      s2 = fmaf(x[i + 2], U[i + 2][jj], s2);
      s3 = fmaf(x[i + 3], U[i + 3][jj], s3);
    }
#pragma unroll
    for (int i = (jj / 4) * 4; i < jj; ++i) s0 = fmaf(x[i], U[i][jj], s0);
    const float a = Arow[jj] - ((s0 + s1) + (s2 + s3));
    x[jj] = a / U[jj][jj];
    Arow[jj] = x[jj];
  }
}

__device__ void ph_trsm(float* sm, float* F, int k, int vb) {
  const int c0 = k * NBK;
  const int colstart = c0 + NBK;
  const int ncols = D - colstart;
  float (*Lw)[65] = (float(*)[65])sm;
  const int tid = threadIdx.x;
  for (int e = tid; e < 4096; e += 256) { const int r = e >> 6, c = e & 63; Lw[r][c] = F[(size_t)(c0 + r) * D + c0 + c]; }
  __syncthreads();
  const int cidx = vb * 256 + tid;
  if (cidx >= ncols) return;
  const int col = colstart + cidx;
  float x[64];
#pragma unroll
  for (int i = 0; i < 64; ++i) {
    float s0 = 0.f, s1 = 0.f, s2 = 0.f, s3 = 0.f;
#pragma unroll
    for (int j = 0; j + 3 < i; j += 4) {
      s0 = fmaf(Lw[i][j], x[j], s0);
      s1 = fmaf(Lw[i][j + 1], x[j + 1], s1);
      s2 = fmaf(Lw[i][j + 2], x[j + 2], s2);
      s3 = fmaf(Lw[i][j + 3], x[j + 3], s3);
    }
#pragma unroll
    for (int j = (i / 4) * 4; j < i; ++j) s0 = fmaf(Lw[i][j], x[j], s0);
    const float a = F[(size_t)(c0 + i) * D + col] - ((s0 + s1) + (s2 + s3));
    x[i] = a;
    F[(size_t)(c0 + i) * D + col] = a;
  }
}

__device__ void ph_gemm_nn(float* sm, float* F, int k, int vbx, int vby) {
  const int c0 = k * NBK;
  const int o = c0 + NBK;
  float (*As)[68] = (float(*)[68])sm;
  float (*Bs)[68] = (float(*)[68])&sm[4352];
  const int tid = threadIdx.x;
  const int cc0 = o + vbx * 64;
  const int r0 = o + vby * 64;
  for (int e = tid; e < 4096; e += 256) {
    const int r = e >> 6, c = e & 63;
    As[c][r] = F[(size_t)(r0 + r) * D + c0 + c];
    Bs[r][c] = F[(size_t)(c0 + r) * D + cc0 + c];
  }
  __syncthreads();
  float acc[4][4] = {};
  tile_fma(As, Bs, acc, tid & 15, tid >> 4);
  const int tx = tid & 15, ty = tid >> 4;
  for (int i = 0; i < 4; ++i)
    for (int j = 0; j < 4; ++j)
      F[(size_t)(r0 + ty * 4 + i) * D + cc0 + tx * 4 + j] -= acc[i][j];
  __syncthreads();
}

__device__ void ph_fsolve(float* sm, const float* F, float* Y, int k, int vb) {
  float (*T)[65] = (float(*)[65])sm;
  const int tid = threadIdx.x;
  const int c0 = k * NBK;
  for (int e = tid; e < 4096; e += 256) { const int r = e >> 6, c = e & 63; T[c][r] = F[(size_t)(c0 + r) * D + c0 + c]; }
  __syncthreads();
  const int col = vb * 256 + tid;
  float x[64];
#pragma unroll
  for (int i = 0; i < 64; ++i) {
    float s0 = 0.f, s1 = 0.f, s2 = 0.f, s3 = 0.f;
#pragma unroll
    for (int j = 0; j + 3 < i; j += 4) {
      s0 = fmaf(T[i][j], x[j], s0);
      s1 = fmaf(T[i][j + 1], x[j + 1], s1);
      s2 = fmaf(T[i][j + 2], x[j + 2], s2);
      s3 = fmaf(T[i][j + 3], x[j + 3], s3);
    }
#pragma unroll
    for (int j = (i / 4) * 4; j < i; ++j) s0 = fmaf(T[i][j], x[j], s0);
    const float a = Y[(size_t)(c0 + i) * D + col] - ((s0 + s1) + (s2 + s3));
    x[i] = a / T[i][i];
    Y[(size_t)(c0 + i) * D + col] = x[i];
  }
  __syncthreads();
}

__device__ void ph_bsolve(float* sm, const float* F, float* Y, int k, int vb) {
  float (*T)[65] = (float(*)[65])sm;
  const int tid = threadIdx.x;
  const int c0 = k * NBK;
  for (int e = tid; e < 4096; e += 256) { const int r = e >> 6, c = e & 63; T[c][r] = F[(size_t)(c0 + r) * D + c0 + c]; }
  __syncthreads();
  const int col = vb * 256 + tid;
  float x[64];
#pragma unroll
  for (int i = 63; i >= 0; --i) {
    float s0 = 0.f, s1 = 0.f, s2 = 0.f, s3 = 0.f;
#pragma unroll
    for (int j = i + 1; j + 3 < 64; j += 4) {
      s0 = fmaf(T[i][j], x[j], s0);
      s1 = fmaf(T[i][j + 1], x[j + 1], s1);
      s2 = fmaf(T[i][j + 2], x[j + 2], s2);
      s3 = fmaf(T[i][j + 3], x[j + 3], s3);
    }
#pragma unroll
    for (int j = i + 1 + (((63 - i) / 4) * 4); j < 64; ++j) s0 = fmaf(T[i][j], x[j], s0);
    const float a = Y[(size_t)(c0 + i) * D + col] - ((s0 + s1) + (s2 + s3));
    x[i] = a;
    Y[(size_t)(c0 + i) * D + col] = a;
  }
  __syncthreads();
}

__device__ void ph_tn(float* sm, const float* F, float* Y, int k, int rlo, int vbx, int vby) {
  const int c0 = k * NBK;
  float (*As)[68] = (float(*)[68])sm;
  float (*Bs)[68] = (float(*)[68])&sm[4352];
  const int tid = threadIdx.x;
  const int cc0 = vbx * 64;
  const int r0 = rlo + vby * 64;
  for (int e = tid; e < 4096; e += 256) {
    const int r = e >> 6, c = e & 63;
    As[r][c] = F[(size_t)(c0 + r) * D + r0 + c];
    Bs[r][c] = Y[(size_t)(c0 + r) * D + cc0 + c];
  }
  __syncthreads();
  float acc[4][4] = {};
  tile_fma(As, Bs, acc, tid & 15, tid >> 4);
  const int tx = tid & 15, ty = tid >> 4;
  for (int i = 0; i < 4; ++i)
    for (int j = 0; j < 4; ++j)
      Y[(size_t)(r0 + ty * 4 + i) * D + cc0 + tx * 4 + j] -= acc[i][j];
  __syncthreads();
}

__device__ void ph_scatter(const float* Y, float* Wm, const int* perm, int vb) {
  const int i = vb >> 2;
  const int c = (vb & 3) * 256 + threadIdx.x;
  Wm[(size_t)perm[i] * D + c] = Y[(size_t)i * D + c];
}

__device__ void ph_round(float* sm, const float* yout, const float* Wm, const float* cmat,
                         float* t, int vbx, int vby) {
  float (*As)[68] = (float(*)[68])sm;
  float (*Bs)[68] = (float(*)[68])&sm[4352];
  const int tid = threadIdx.x;
  const int i0 = vbx * 64;
  const int b0 = vby * 64;
  float acc[4][4] = {};
  for (int kb = 0; kb < D; kb += 64) {
    for (int e = tid; e < 4096; e += 256) {
      const int r = e >> 6, c = e & 63;
      As[c][r] = yout[(size_t)(b0 + r) * D + kb + c];
      Bs[r][c] = Wm[(size_t)(kb + r) * D + i0 + c];
    }
    __syncthreads();
    tile_fma(As, Bs, acc, tid & 15, tid >> 4);
    __syncthreads();
  }
  const int tx = tid & 15, ty = tid >> 4;
  for (int i = 0; i < 4; ++i)
    for (int j = 0; j < 4; ++j) {
      const int b = b0 + ty * 4 + i, col = i0 + tx * 4 + j;
      const float v = yout[(size_t)b * D + col] - XRHOV * acc[i][j] - RHOV * cmat[(size_t)b * D + col];
      t[(size_t)b * D + col] = v;
    }
  __syncthreads();
}

// ---------------- block-local Dykstra (t,q in LDS; y -> yout every iter) ----------------
__device__ void dyk_state_init(float* sm, const KArgs& a, int r0) {
  float4* ts4 = (float4*)(sm + TS);
  float4* qs4 = (float4*)(sm + QS);
  const float4* t4 = (const float4*)(a.t + (size_t)r0 * D);
  for (int e = threadIdx.x; e < 1024; e += 256) {
    ts4[e] = t4[e];
    qs4[e] = make_float4(0.f, 0.f, 0.f, 0.f);
  }
  if (threadIdx.x < 256) sm[BS + threadIdx.x] = a.b[threadIdx.x];
  __syncthreads();
}

__device__ void dyk_iter(float* sm, const KArgs& a, int r0, int it, int base) {
  const int tid = threadIdx.x;
  float* ts = sm + TS;
  float* qs = sm + QS;
  float* us = sm + US;
  float* part = sm + PART;

  // u-phase: part[ks][r][m] = sum over k-quarter of ts[r][k]*At[k][m]
  const int m4 = tid & 63, ks = tid >> 6;
  const float* AtB = a.At + (size_t)ks * 256 * MC + m4 * 4;
  float4 ua[4];
#pragma unroll
  for (int r = 0; r < 4; ++r) ua[r] = make_float4(0.f, 0.f, 0.f, 0.f);
  const int kb = ks * 256;
#pragma unroll 2
  for (int k4 = 0; k4 < 64; ++k4) {
    float t0[4], t1[4], t2[4], t3[4];
    *(float4*)t0 = *(const float4*)&ts[kb + k4 * 4];
    *(float4*)t1 = *(const float4*)&ts[1024 + kb + k4 * 4];
    *(float4*)t2 = *(const float4*)&ts[2048 + kb + k4 * 4];
    *(float4*)t3 = *(const float4*)&ts[3072 + kb + k4 * 4];
#pragma unroll
    for (int j = 0; j < 4; ++j) {
      const float4 av = *(const float4*)(AtB + (size_t)(k4 * 4 + j) * MC);
      ua[0].x = fmaf(t0[j], av.x, ua[0].x); ua[0].y = fmaf(t0[j], av.y, ua[0].y);
      ua[0].z = fmaf(t0[j], av.z, ua[0].z); ua[0].w = fmaf(t0[j], av.w, ua[0].w);
      ua[1].x = fmaf(t1[j], av.x, ua[1].x); ua[1].y = fmaf(t1[j], av.y, ua[1].y);
      ua[1].z = fmaf(t1[j], av.z, ua[1].z); ua[1].w = fmaf(t1[j], av.w, ua[1].w);
      ua[2].x = fmaf(t2[j], av.x, ua[2].x); ua[2].y = fmaf(t2[j], av.y, ua[2].y);
      ua[2].z = fmaf(t2[j], av.z, ua[2].z); ua[2].w = fmaf(t2[j], av.w, ua[2].w);
      ua[3].x = fmaf(t3[j], av.x, ua[3].x); ua[3].y = fmaf(t3[j], av.y, ua[3].y);
      ua[3].z = fmaf(t3[j], av.z, ua[3].z); ua[3].w = fmaf(t3[j], av.w, ua[3].w);
    }
  }
#pragma unroll
  for (int r = 0; r < 4; ++r) ((float4*)part)[(ks * 4 + r) * 64 + m4] = ua[r];
  __syncthreads();

  // reduce partials: us[r][m] = sum_ks part - b[m]
  {
    const int m = tid;
#pragma unroll
    for (int r = 0; r < 4; ++r)
      us[r * 256 + m] = part[r * 256 + m] + part[1024 + r * 256 + m] +
                        part[2048 + r * 256 + m] + part[3072 + r * 256 + m] - sm[BS + m];
  }
  __syncthreads();

  // y-phase: y[r][d] = ts[r][d] - sum_m us[r][m]*AAt[m][d]
  float4 ya[4];
#pragma unroll
  for (int r = 0; r < 4; ++r) ya[r] = make_float4(0.f, 0.f, 0.f, 0.f);
  const float4* AAB = (const float4*)a.AAt;
#pragma unroll 2
  for (int mi = 0; mi < 64; ++mi) {
    float u0[4], u1[4], u2[4], u3[4];
    *(float4*)u0 = *(const float4*)&us[mi * 4];
    *(float4*)u1 = *(const float4*)&us[256 + mi * 4];
    *(float4*)u2 = *(const float4*)&us[512 + mi * 4];
    *(float4*)u3 = *(const float4*)&us[768 + mi * 4];
#pragma unroll
    for (int j = 0; j < 4; ++j) {
      const float4 w = AAB[(size_t)(mi * 4 + j) * (D / 4) + tid];
      ya[0].x = fmaf(u0[j], w.x, ya[0].x); ya[0].y = fmaf(u0[j], w.y, ya[0].y);
      ya[0].z = fmaf(u0[j], w.z, ya[0].z); ya[0].w = fmaf(u0[j], w.w, ya[0].w);
      ya[1].x = fmaf(u1[j], w.x, ya[1].x); ya[1].y = fmaf(u1[j], w.y, ya[1].y);
      ya[1].z = fmaf(u1[j], w.z, ya[1].z); ya[1].w = fmaf(u1[j], w.w, ya[1].w);
      ya[2].x = fmaf(u2[j], w.x, ya[2].x); ya[2].y = fmaf(u2[j], w.y, ya[2].y);
      ya[2].z = fmaf(u2[j], w.z, ya[2].z); ya[2].w = fmaf(u2[j], w.w, ya[2].w);
      ya[3].x = fmaf(u3[j], w.x, ya[3].x); ya[3].y = fmaf(u3[j], w.y, ya[3].y);
      ya[3].z = fmaf(u3[j], w.z, ya[3].z); ya[3].w = fmaf(u3[j], w.w, ya[3].w);
    }
  }

  float nmax = 0.f;
#pragma unroll
  for (int r = 0; r < 4; ++r) {
    const float4 tv = *(const float4*)&ts[r * 1024 + tid * 4];
    float4 y;
    y.x = tv.x - ya[r].x; y.y = tv.y - ya[r].y;
    y.z = tv.z - ya[r].z; y.w = tv.w - ya[r].w;
    ((float4*)a.yout)[(size_t)(r0 + r) * (D / 4) + tid] = y;
    const float4 qv = *(const float4*)&qs[r * 1024 + tid * 4];
    float4 tn, qn;
    { const float yq = y.x + qv.x, xn = fmaxf(yq, 0.f); tn.x = xn + (tv.x - y.x); qn.x = yq - xn; }
    { const float yq = y.y + qv.y, xn = fmaxf(yq, 0.f); tn.y = xn + (tv.y - y.y); qn.y = yq - xn; }
    { const float yq = y.z + qv.z, xn = fmaxf(yq, 0.f); tn.z = xn + (tv.z - y.z); qn.z = yq - xn; }
    { const float yq = y.w + qv.w, xn = fmaxf(yq, 0.f); tn.w = xn + (tv.w - y.w); qn.w = yq - xn; }
    *(float4*)&ts[r * 1024 + tid * 4] = tn;
    *(float4*)&qs[r * 1024 + tid * 4] = qn;
    nmax = fmaxf(nmax, -y.x); nmax = fmaxf(nmax, -y.y);
    nmax = fmaxf(nmax, -y.z); nmax = fmaxf(nmax, -y.w);
  }
#pragma unroll
  for (int off = 32; off > 0; off >>= 1) nmax = fmaxf(nmax, __shfl_down(nmax, off));
  if ((tid & 63) == 0) sm[RED + (tid >> 6)] = nmax;
  __syncthreads();
  if (tid == 0) {
    const float m = fmaxf(fmaxf(sm[RED], sm[RED + 1]), fmaxf(sm[RED + 2], sm[RED + 3]));
    atomicMax((int*)&a.err[base + it], __float_as_int(m));
  }
}

// one Dykstra round with per-iteration flat barrier and exact uniform break
__device__ void dyk_round(float* sm, const KArgs& a, int bid, int base, unsigned& genG) {
  const int r0 = bid * 4;
  dyk_state_init(sm, a, r0);
  for (int it = 0; it < MAXIT; ++it) {
    dyk_iter(sm, a, r0, it, base);
    fbar(a.slotsG, bid, NGA, ++genG);  // err[base+it] is final after this
    const int eb = __hip_atomic_load((int*)&a.err[base + it], __ATOMIC_RELAXED,
                                     __HIP_MEMORY_SCOPE_AGENT);
    if (__int_as_float(eb) < TOLV) break;  // yout == y(it*) already written
  }
}

// ---------------- the megakernel ----------------
__global__ __launch_bounds__(256, 1) void mega(KArgs a) {
  __shared__ alignas(16) float sm[SMF];
  const int bid = blockIdx.x;
  const int tid = threadIdx.x;
  unsigned genF = 0, genG = 0;

  // ---- joint init: t=-rho*c, perm, F/Ybuf prep, At/AAt transposes ----
  {
    const int gtid = bid * 256 + tid;
    for (int i = gtid; i < BSZ * D; i += GRID * 256) a.t[i] = -RHOV * a.c[i];
    if (gtid < D) a.perm[gtid] = gtid;
  }
  for (int vb = bid; vb < 384; vb += GRID) {
    if (vb < 256) ph_prep(sm, vb, a.L, a.Lam, a.F, a.Ybuf);
    else if (vb < 320) { const int tt = vb - 256; ph_transpose(sm, a.A, a.At, MC, D, tt & 3, tt >> 2); }
    else { const int tt = vb - 320; ph_transpose(sm, a.AA, a.AAt, D, MC, tt & 15, tt >> 4); }
  }
  fbar(a.slotsF, bid, GRID, ++genF);

  if (bid < NGA) {
    // ======== group A: round-0 Dykstra (overlaps group B's M-build) ========
    dyk_round(sm, a, bid, 0, genG);
    fbar(a.slotsF, bid, GRID, ++genF);  // join: Wm ready, yout(r0) ready
    // ======== rounds 1,2 on group A only ========
    for (int r = 1; r < N_ROUNDS; ++r) {
      ph_round(sm, a.yout, a.Wm, a.c, a.t, bid & 15, bid >> 4);  // 128 tiles, 1 each
      fbar(a.slotsG, bid, NGA, ++genG);
      dyk_round(sm, a, bid, r * MAXIT, genG);
    }
  } else {
    // ======== group B: LU + single solve pass + scatter ========
    unsigned* slotsB = a.slotsG + NGB * 16;
    const int vbid = bid - NGA;
    for (int k = 0; k < NPAN; ++k) {
      if (vbid == 0) ph_lu_diag(sm, a.F, a.perm, k);
      fbar(slotsB, vbid, NGB, ++genG);
      const int rem = D - (k + 1) * NBK;
      if (rem > 0) {
        const int nvb = (rem + 255) / 256;
        for (int vb = vbid; vb < 2 * nvb; vb += NGB) {
          if (vb < nvb) ph_l21(sm, a.F, k, vb);
          else ph_trsm(sm, a.F, k, vb - nvb);
        }
        fbar(slotsB, vbid, NGB, ++genG);
        const int nt = rem / 64;
        for (int vb = vbid; vb < nt * nt; vb += NGB) ph_gemm_nn(sm, a.F, k, vb % nt, vb / nt);
        fbar(slotsB, vbid, NGB, ++genG);
      }
    }
    for (int k = 0; k < NPAN; ++k) {
      for (int vb = vbid; vb < 4; vb += NGB) ph_fsolve(sm, a.F, a.Ybuf, k, vb);
      fbar(slotsB, vbid, NGB, ++genG);
      const int rem = D - (k + 1) * NBK;
      if (rem > 0) {
        for (int vb = vbid; vb < 16 * (rem / 64); vb += NGB)
          ph_tn(sm, a.F, a.Ybuf, k, (k + 1) * NBK, vb & 15, vb >> 4);
        fbar(slotsB, vbid, NGB, ++genG);
      }
    }
    for (int k = NPAN - 1; k >= 0; --k) {
      for (int vb = vbid; vb < 4; vb += NGB) ph_bsolve(sm, a.F, a.Ybuf, k, vb);
      fbar(slotsB, vbid, NGB, ++genG);
      if (k > 0) {
        for (int vb = vbid; vb < 16 * k; vb += NGB)
          ph_tn(sm, a.F, a.Ybuf, k, 0, vb & 15, vb >> 4);
        fbar(slotsB, vbid, NGB, ++genG);
      }
    }
    for (int vb = vbid; vb < 4 * D; vb += NGB) ph_scatter(a.Ybuf, a.Wm, a.perm, vb);
    fbar(a.slotsF, bid, GRID, ++genF);  // join; group B done
  }
}

extern "C" void kernel_launch(void* const* d_in, const int* in_sizes, int n_in,
                              void* d_out, int out_size, void* d_ws, size_t ws_size,
                              hipStream_t stream) {
  (void)in_sizes; (void)n_in; (void)out_size; (void)ws_size;
  KArgs a;
  a.c   = (const float*)d_in[0];
  a.A   = (const float*)d_in[1];
  a.b   = (const float*)d_in[2];
  a.AA  = (const float*)d_in[3];
  a.L   = (const float*)d_in[4];
  a.Lam = (const float*)d_in[5];
  a.yout = (float*)d_out;

  // ctrl region (zeroed every call; ws is NOT re-poisoned between replays)
  char* w = (char*)d_ws;
  a.slotsF = (unsigned*)w;              // 256 x 64B
  a.slotsG = (unsigned*)(w + 16384);    // 256 x 64B (A: [0,128), B: [128,256))
  a.err    = (float*)(w + 32768);       // 90 slots
  w += 36864;
  a.F    = (float*)w; w += (size_t)D * D * 4;
  a.Ybuf = (float*)w; w += (size_t)D * D * 4;
  a.Wm   = (float*)w; w += (size_t)D * D * 4;
  a.t    = (float*)w; w += (size_t)BSZ * D * 4;
  a.At   = (float*)w; w += (size_t)D * MC * 4;
  a.AAt  = (float*)w; w += (size_t)MC * D * 4;
  a.perm = (int*)w;   w += (size_t)D * 4;

  hipMemsetAsync(d_ws, 0, 36864, stream);
  mega<<<dim3(GRID), dim3(256), 0, stream>>>(a);
}

// Round 7
// 6066.183 us; speedup vs baseline: 2.7746x; 1.1075x over previous
//
#include <hip/hip_runtime.h>

#define D      1024
#define BSZ    512
#define MC     256
#define NBK    64
#define NPAN   16
#define N_ROUNDS 3
#define MAXIT  30
#define TOLV   0.01f
#define RHOV   3.0f
#define XRHOV  0.5f
#define GRID   256
#define NGA    128   // group A: Dykstra blocks (4 rows each)
#define NGB    128   // group B: LU/solve blocks

// dyk LDS float offsets
#define TS   0
#define QS   4096
#define US   8192
#define PART 9216
#define BS   13312
#define RED  13568
#define SMF  13600

struct KArgs {
  const float *c, *A, *b, *AA, *L, *Lam;
  float *yout, *F, *Ybuf, *Wm;
  float *t, *err, *At, *AAt;
  int *perm, *rmap;
  unsigned *slotsF, *slotsG;  // full-grid / per-group barrier slots (64B stride)
};

// ---------------- flat grid barrier: own-slot store + parallel poll ----------------
__device__ __forceinline__ void fbar(unsigned* slots, int lid, int count, unsigned target) {
  __syncthreads();
  if (threadIdx.x == 0) {
    __builtin_amdgcn_fence(__ATOMIC_RELEASE, "agent");
    __hip_atomic_store(&slots[lid * 16], target, __ATOMIC_RELAXED, __HIP_MEMORY_SCOPE_AGENT);
  }
  for (int i = threadIdx.x; i < count; i += 256)
    while (__hip_atomic_load(&slots[i * 16], __ATOMIC_RELAXED, __HIP_MEMORY_SCOPE_AGENT) < target)
      __builtin_amdgcn_s_sleep(1);
  __builtin_amdgcn_fence(__ATOMIC_ACQUIRE, "agent");
  __syncthreads();
}

// ---------------- shared tile FMA (64x64 tile, 4x4 per thread) ----------------
__device__ __forceinline__ void tile_fma(const float (*As)[68], const float (*Bs)[68],
                                         float acc[4][4], const int tx, const int ty) {
#pragma unroll 8
  for (int kk = 0; kk < 64; ++kk) {
    const float4 a4 = *(const float4*)(&As[kk][ty * 4]);
    const float4 b4 = *(const float4*)(&Bs[kk][tx * 4]);
    const float a0 = a4.x, a1 = a4.y, a2 = a4.z, a3 = a4.w;
    const float b0 = b4.x, b1 = b4.y, b2 = b4.z, b3 = b4.w;
    acc[0][0] = fmaf(a0, b0, acc[0][0]); acc[0][1] = fmaf(a0, b1, acc[0][1]);
    acc[0][2] = fmaf(a0, b2, acc[0][2]); acc[0][3] = fmaf(a0, b3, acc[0][3]);
    acc[1][0] = fmaf(a1, b0, acc[1][0]); acc[1][1] = fmaf(a1, b1, acc[1][1]);
    acc[1][2] = fmaf(a1, b2, acc[1][2]); acc[1][3] = fmaf(a1, b3, acc[1][3]);
    acc[2][0] = fmaf(a2, b0, acc[2][0]); acc[2][1] = fmaf(a2, b1, acc[2][1]);
    acc[2][2] = fmaf(a2, b2, acc[2][2]); acc[2][3] = fmaf(a2, b3, acc[2][3]);
    acc[3][0] = fmaf(a3, b0, acc[3][0]); acc[3][1] = fmaf(a3, b1, acc[3][1]);
    acc[3][2] = fmaf(a3, b2, acc[3][2]); acc[3][3] = fmaf(a3, b3, acc[3][3]);
  }
}

// ---------------- prep / transpose ----------------
__device__ void ph_prep(float* sm, int vb, const float* L, const float* Lam,
                        float* F, float* Ybuf) {
  float (*tile)[65] = (float(*)[65])sm;
  const int bi = vb >> 4, bj = vb & 15;
  const int tx = threadIdx.x & 63, ty4 = threadIdx.x >> 6;
  const int i0 = bi * 64, j0 = bj * 64;
  for (int r = ty4; r < 64; r += 4) {
    const float v = L[(size_t)(i0 + r) * D + j0 + tx];
    F[(size_t)(i0 + r) * D + j0 + tx] = v;
    tile[r][tx] = v;
  }
  __syncthreads();
  for (int r = ty4; r < 64; r += 4) {
    const int j = j0 + r;
    Ybuf[(size_t)j * D + i0 + tx] = Lam[j] * tile[tx][r];
  }
  __syncthreads();
}

__device__ void ph_transpose(float* sm, const float* src, float* dst,
                             int srows, int scols, int tr, int tc) {
  float (*tile)[65] = (float(*)[65])sm;
  const int tx = threadIdx.x & 63, ty = threadIdx.x >> 6;
  for (int r = ty; r < 64; r += 4)
    tile[r][tx] = src[(size_t)(tr * 64 + r) * scols + tc * 64 + tx];
  __syncthreads();
  for (int r = ty; r < 64; r += 4)
    dst[(size_t)(tc * 64 + r) * srows + tr * 64 + tx] = tile[tx][r];
  __syncthreads();
}

// ---------------- LU: LDS-only pivoting with deferred off-panel swaps ----------------
__device__ void ph_lu_diag(float* sm, float* F, int* perm, int* rmap, int k) {
  float (*blk)[65] = (float(*)[65])sm;
  int* pr_sh = (int*)&sm[8960];
  int* rmp   = (int*)&sm[8964];  // 64 ints
  const int tid = threadIdx.x;
  const int c0 = k * NBK;
  for (int e = tid; e < 4096; e += 256) {
    const int r = e >> 6, c = e & 63;
    blk[r][c] = F[(size_t)(c0 + r) * D + c0 + c];
  }
  if (tid < 64) rmp[tid] = tid;
  __syncthreads();
  for (int j = 0; j < 64; ++j) {
    if (tid < 64) {
      float v = (tid >= j) ? fabsf(blk[tid][j]) : -1.0f;
      int ridx = tid;
      for (int off = 32; off > 0; off >>= 1) {
        const float ov = __shfl_down(v, off);
        const int oi = __shfl_down(ridx, off);
        if (ov > v) { v = ov; ridx = oi; }
      }
      if (tid == 0) *pr_sh = ridx;
    }
    __syncthreads();
    const int pr = *pr_sh;
    if (pr != j) {
      if (tid < 64) { const float a = blk[j][tid], b = blk[pr][tid]; blk[j][tid] = b; blk[pr][tid] = a; }
      if (tid == 0) {
        int t = perm[c0 + j]; perm[c0 + j] = perm[c0 + pr]; perm[c0 + pr] = t;
        t = rmp[j]; rmp[j] = rmp[pr]; rmp[pr] = t;
      }
    }
    __syncthreads();
    const float inv = 1.0f / blk[j][j];
    const int r = tid >> 2, l4 = tid & 3;
    if (r > j) {
      const float lval = blk[r][j] * inv;
      if (l4 == 0) blk[r][j] = lval;
      for (int c = j + 1 + l4; c < 64; c += 4)
        blk[r][c] = fmaf(-lval, blk[j][c], blk[r][c]);
    }
    __syncthreads();
  }
  for (int e = tid; e < 4096; e += 256) {
    const int r = e >> 6, c = e & 63;
    F[(size_t)(c0 + r) * D + c0 + c] = blk[r][c];
  }
  if (tid < 64) rmap[tid] = rmp[tid];
  __syncthreads();
}

// apply band-row permutation to a 64-col chunk left of the panel (cols < c0)
__device__ void ph_leftperm(float* sm, float* F, const int* rmap, int k, int chunk) {
  float (*tile)[65] = (float(*)[65])sm;
  int* rm = (int*)&sm[8960];
  const int tid = threadIdx.x;
  const int c0 = k * NBK;
  const int col0 = chunk * 64;
  if (tid < 64) rm[tid] = rmap[tid];
  __syncthreads();
  for (int e = tid; e < 4096; e += 256) {
    const int r = e >> 6, c = e & 63;
    tile[r][c] = F[(size_t)(c0 + rm[r]) * D + col0 + c];
  }
  __syncthreads();
  for (int e = tid; e < 4096; e += 256) {
    const int r = e >> 6, c = e & 63;
    F[(size_t)(c0 + r) * D + col0 + c] = tile[r][c];
  }
}

// L21 = A21 * U11^-1, register-prefetched row solve
__device__ void ph_l21(float* sm, float* F, int k, int vb) {
  const int c0 = k * NBK;
  const int row0 = c0 + NBK;
  const int nrows = D - row0;
  float (*U)[65] = (float(*)[65])sm;
  const int tid = threadIdx.x;
  for (int e = tid; e < 4096; e += 256) { const int r = e >> 6, c = e & 63; U[r][c] = F[(size_t)(c0 + r) * D + c0 + c]; }
  __syncthreads();
  const int r = vb * 256 + tid;
  if (r >= nrows) return;
  float* Arow = &F[(size_t)(row0 + r) * D + c0];
  float x[64];
#pragma unroll
  for (int i = 0; i < 16; ++i) *(float4*)&x[i * 4] = *(const float4*)&Arow[i * 4];
#pragma unroll
  for (int jj = 0; jj < 64; ++jj) {
    float s0 = 0.f, s1 = 0.f, s2 = 0.f, s3 = 0.f;
#pragma unroll
    for (int i = 0; i + 3 < jj; i += 4) {
      s0 = fmaf(x[i], U[i][jj], s0);
      s1 = fmaf(x[i + 1], U[i + 1][jj], s1);
      s2 = fmaf(x[i + 2], U[i + 2][jj], s2);
      s3 = fmaf(x[i + 3], U[i + 3][jj], s3);
    }
#pragma unroll
    for (int i = (jj / 4) * 4; i < jj; ++i) s0 = fmaf(x[i], U[i][jj], s0);
    const float a = x[jj] - ((s0 + s1) + (s2 + s3));
    x[jj] = a / U[jj][jj];
  }
#pragma unroll
  for (int i = 0; i < 16; ++i) *(float4*)&Arow[i * 4] = *(const float4*)&x[i * 4];
}

// U12 = Lam11^-1 * P * A12: reads band rows through rmap (deferred swap), writes canonical
__device__ void ph_trsm(float* sm, float* F, const int* rmap, int k, int vb) {
  const int c0 = k * NBK;
  const int colstart = c0 + NBK;
  const int ncols = D - colstart;
  float (*Lw)[65] = (float(*)[65])sm;
  int* rm = (int*)&sm[8960];
  const int tid = threadIdx.x;
  for (int e = tid; e < 4096; e += 256) { const int r = e >> 6, c = e & 63; Lw[r][c] = F[(size_t)(c0 + r) * D + c0 + c]; }
  if (tid < 64) rm[tid] = rmap[tid];
  __syncthreads();
  const int cidx = vb * 256 + tid;
  if (cidx >= ncols) return;
  const int col = colstart + cidx;
  float x[64];
#pragma unroll
  for (int i = 0; i < 64; ++i) x[i] = F[(size_t)(c0 + rm[i]) * D + col];
#pragma unroll
  for (int i = 0; i < 64; ++i) {
    float s0 = 0.f, s1 = 0.f, s2 = 0.f, s3 = 0.f;
#pragma unroll
    for (int j = 0; j + 3 < i; j += 4) {
      s0 = fmaf(Lw[i][j], x[j], s0);
      s1 = fmaf(Lw[i][j + 1], x[j + 1], s1);
      s2 = fmaf(Lw[i][j + 2], x[j + 2], s2);
      s3 = fmaf(Lw[i][j + 3], x[j + 3], s3);
    }
#pragma unroll
    for (int j = (i / 4) * 4; j < i; ++j) s0 = fmaf(Lw[i][j], x[j], s0);
    x[i] = x[i] - ((s0 + s1) + (s2 + s3));
  }
#pragma unroll
  for (int i = 0; i < 64; ++i) F[(size_t)(c0 + i) * D + col] = x[i];
}

__device__ void ph_gemm_nn(float* sm, float* F, int k, int vbx, int vby) {
  const int c0 = k * NBK;
  const int o = c0 + NBK;
  float (*As)[68] = (float(*)[68])sm;
  float (*Bs)[68] = (float(*)[68])&sm[4352];
  const int tid = threadIdx.x;
  const int cc0 = o + vbx * 64;
  const int r0 = o + vby * 64;
  for (int e = tid; e < 4096; e += 256) {
    const int r = e >> 6, c = e & 63;
    As[c][r] = F[(size_t)(r0 + r) * D + c0 + c];
    Bs[r][c] = F[(size_t)(c0 + r) * D + cc0 + c];
  }
  __syncthreads();
  float acc[4][4] = {};
  tile_fma(As, Bs, acc, tid & 15, tid >> 4);
  const int tx = tid & 15, ty = tid >> 4;
  for (int i = 0; i < 4; ++i)
    for (int j = 0; j < 4; ++j)
      F[(size_t)(r0 + ty * 4 + i) * D + cc0 + tx * 4 + j] -= acc[i][j];
  __syncthreads();
}

__device__ void ph_fsolve(float* sm, const float* F, float* Y, int k, int vb) {
  float (*T)[65] = (float(*)[65])sm;
  const int tid = threadIdx.x;
  const int c0 = k * NBK;
  for (int e = tid; e < 4096; e += 256) { const int r = e >> 6, c = e & 63; T[c][r] = F[(size_t)(c0 + r) * D + c0 + c]; }
  __syncthreads();
  const int col = vb * 256 + tid;
  float x[64];
#pragma unroll
  for (int i = 0; i < 64; ++i) x[i] = Y[(size_t)(c0 + i) * D + col];
#pragma unroll
  for (int i = 0; i < 64; ++i) {
    float s0 = 0.f, s1 = 0.f, s2 = 0.f, s3 = 0.f;
#pragma unroll
    for (int j = 0; j + 3 < i; j += 4) {
      s0 = fmaf(T[i][j], x[j], s0);
      s1 = fmaf(T[i][j + 1], x[j + 1], s1);
      s2 = fmaf(T[i][j + 2], x[j + 2], s2);
      s3 = fmaf(T[i][j + 3], x[j + 3], s3);
    }
#pragma unroll
    for (int j = (i / 4) * 4; j < i; ++j) s0 = fmaf(T[i][j], x[j], s0);
    const float a = x[i] - ((s0 + s1) + (s2 + s3));
    x[i] = a / T[i][i];
  }
#pragma unroll
  for (int i = 0; i < 64; ++i) Y[(size_t)(c0 + i) * D + col] = x[i];
  __syncthreads();
}

__device__ void ph_bsolve(float* sm, const float* F, float* Y, int k, int vb) {
  float (*T)[65] = (float(*)[65])sm;
  const int tid = threadIdx.x;
  const int c0 = k * NBK;
  for (int e = tid; e < 4096; e += 256) { const int r = e >> 6, c = e & 63; T[c][r] = F[(size_t)(c0 + r) * D + c0 + c]; }
  __syncthreads();
  const int col = vb * 256 + tid;
  float x[64];
#pragma unroll
  for (int i = 0; i < 64; ++i) x[i] = Y[(size_t)(c0 + i) * D + col];
#pragma unroll
  for (int i = 63; i >= 0; --i) {
    float s0 = 0.f, s1 = 0.f, s2 = 0.f, s3 = 0.f;
#pragma unroll
    for (int j = i + 1; j + 3 < 64; j += 4) {
      s0 = fmaf(T[i][j], x[j], s0);
      s1 = fmaf(T[i][j + 1], x[j + 1], s1);
      s2 = fmaf(T[i][j + 2], x[j + 2], s2);
      s3 = fmaf(T[i][j + 3], x[j + 3], s3);
    }
#pragma unroll
    for (int j = i + 1 + (((63 - i) / 4) * 4); j < 64; ++j) s0 = fmaf(T[i][j], x[j], s0);
    x[i] = x[i] - ((s0 + s1) + (s2 + s3));
  }
#pragma unroll
  for (int i = 0; i < 64; ++i) Y[(size_t)(c0 + i) * D + col] = x[i];
  __syncthreads();
}

__device__ void ph_tn(float* sm, const float* F, float* Y, int k, int rlo, int vbx, int vby) {
  const int c0 = k * NBK;
  float (*As)[68] = (float(*)[68])sm;
  float (*Bs)[68] = (float(*)[68])&sm[4352];
  const int tid = threadIdx.x;
  const int cc0 = vbx * 64;
  const int r0 = rlo + vby * 64;
  for (int e = tid; e < 4096; e += 256) {
    const int r = e >> 6, c = e & 63;
    As[r][c] = F[(size_t)(c0 + r) * D + r0 + c];
    Bs[r][c] = Y[(size_t)(c0 + r) * D + cc0 + c];
  }
  __syncthreads();
  float acc[4][4] = {};
  tile_fma(As, Bs, acc, tid & 15, tid >> 4);
  const int tx = tid & 15, ty = tid >> 4;
  for (int i = 0; i < 4; ++i)
    for (int j = 0; j < 4; ++j)
      Y[(size_t)(r0 + ty * 4 + i) * D + cc0 + tx * 4 + j] -= acc[i][j];
  __syncthreads();
}

__device__ void ph_scatter(const float* Y, float* Wm, const int* perm, int vb) {
  const int i = vb >> 2;
  const int c = (vb & 3) * 256 + threadIdx.x;
  Wm[(size_t)perm[i] * D + c] = Y[(size_t)i * D + c];
}

__device__ void ph_round(float* sm, const float* yout, const float* Wm, const float* cmat,
                         float* t, int vbx, int vby) {
  float (*As)[68] = (float(*)[68])sm;
  float (*Bs)[68] = (float(*)[68])&sm[4352];
  const int tid = threadIdx.x;
  const int i0 = vbx * 64;
  const int b0 = vby * 64;
  float acc[4][4] = {};
  for (int kb = 0; kb < D; kb += 64) {
    for (int e = tid; e < 4096; e += 256) {
      const int r = e >> 6, c = e & 63;
      As[c][r] = yout[(size_t)(b0 + r) * D + kb + c];
      Bs[r][c] = Wm[(size_t)(kb + r) * D + i0 + c];
    }
    __syncthreads();
    tile_fma(As, Bs, acc, tid & 15, tid >> 4);
    __syncthreads();
  }
  const int tx = tid & 15, ty = tid >> 4;
  for (int i = 0; i < 4; ++i)
    for (int j = 0; j < 4; ++j) {
      const int b = b0 + ty * 4 + i, col = i0 + tx * 4 + j;
      const float v = yout[(size_t)b * D + col] - XRHOV * acc[i][j] - RHOV * cmat[(size_t)b * D + col];
      t[(size_t)b * D + col] = v;
    }
  __syncthreads();
}

// ---------------- block-local Dykstra (t,q in LDS; y -> yout every iter) ----------------
__device__ void dyk_state_init(float* sm, const KArgs& a, int r0) {
  float4* ts4 = (float4*)(sm + TS);
  float4* qs4 = (float4*)(sm + QS);
  const float4* t4 = (const float4*)(a.t + (size_t)r0 * D);
  for (int e = threadIdx.x; e < 1024; e += 256) {
    ts4[e] = t4[e];
    qs4[e] = make_float4(0.f, 0.f, 0.f, 0.f);
  }
  if (threadIdx.x < 256) sm[BS + threadIdx.x] = a.b[threadIdx.x];
  __syncthreads();
}

__device__ void dyk_iter(float* sm, const KArgs& a, int r0, int it, int base) {
  const int tid = threadIdx.x;
  float* ts = sm + TS;
  float* qs = sm + QS;
  float* us = sm + US;
  float* part = sm + PART;

  // u-phase: part[ks][r][m] = sum over k-quarter of ts[r][k]*At[k][m]
  const int m4 = tid & 63, ks = tid >> 6;
  const float* AtB = a.At + (size_t)ks * 256 * MC + m4 * 4;
  float4 ua[4];
#pragma unroll
  for (int r = 0; r < 4; ++r) ua[r] = make_float4(0.f, 0.f, 0.f, 0.f);
  const int kb = ks * 256;
#pragma unroll 2
  for (int k4 = 0; k4 < 64; ++k4) {
    float t0[4], t1[4], t2[4], t3[4];
    *(float4*)t0 = *(const float4*)&ts[kb + k4 * 4];
    *(float4*)t1 = *(const float4*)&ts[1024 + kb + k4 * 4];
    *(float4*)t2 = *(const float4*)&ts[2048 + kb + k4 * 4];
    *(float4*)t3 = *(const float4*)&ts[3072 + kb + k4 * 4];
#pragma unroll
    for (int j = 0; j < 4; ++j) {
      const float4 av = *(const float4*)(AtB + (size_t)(k4 * 4 + j) * MC);
      ua[0].x = fmaf(t0[j], av.x, ua[0].x); ua[0].y = fmaf(t0[j], av.y, ua[0].y);
      ua[0].z = fmaf(t0[j], av.z, ua[0].z); ua[0].w = fmaf(t0[j], av.w, ua[0].w);
      ua[1].x = fmaf(t1[j], av.x, ua[1].x); ua[1].y = fmaf(t1[j], av.y, ua[1].y);
      ua[1].z = fmaf(t1[j], av.z, ua[1].z); ua[1].w = fmaf(t1[j], av.w, ua[1].w);
      ua[2].x = fmaf(t2[j], av.x, ua[2].x); ua[2].y = fmaf(t2[j], av.y, ua[2].y);
      ua[2].z = fmaf(t2[j], av.z, ua[2].z); ua[2].w = fmaf(t2[j], av.w, ua[2].w);
      ua[3].x = fmaf(t3[j], av.x, ua[3].x); ua[3].y = fmaf(t3[j], av.y, ua[3].y);
      ua[3].z = fmaf(t3[j], av.z, ua[3].z); ua[3].w = fmaf(t3[j], av.w, ua[3].w);
    }
  }
#pragma unroll
  for (int r = 0; r < 4; ++r) ((float4*)part)[(ks * 4 + r) * 64 + m4] = ua[r];
  __syncthreads();

  // reduce partials: us[r][m] = sum_ks part - b[m]
  {
    const int m = tid;
#pragma unroll
    for (int r = 0; r < 4; ++r)
      us[r * 256 + m] = part[r * 256 + m] + part[1024 + r * 256 + m] +
                        part[2048 + r * 256 + m] + part[3072 + r * 256 + m] - sm[BS + m];
  }
  __syncthreads();

  // y-phase: y[r][d] = ts[r][d] - sum_m us[r][m]*AAt[m][d]
  float4 ya[4];
#pragma unroll
  for (int r = 0; r < 4; ++r) ya[r] = make_float4(0.f, 0.f, 0.f, 0.f);
  const float4* AAB = (const float4*)a.AAt;
#pragma unroll 2
  for (int mi = 0; mi < 64; ++mi) {
    float u0[4], u1[4], u2[4], u3[4];
    *(float4*)u0 = *(const float4*)&us[mi * 4];
    *(float4*)u1 = *(const float4*)&us[256 + mi * 4];
    *(float4*)u2 = *(const float4*)&us[512 + mi * 4];
    *(float4*)u3 = *(const float4*)&us[768 + mi * 4];
#pragma unroll
    for (int j = 0; j < 4; ++j) {
      const float4 w = AAB[(size_t)(mi * 4 + j) * (D / 4) + tid];
      ya[0].x = fmaf(u0[j], w.x, ya[0].x); ya[0].y = fmaf(u0[j], w.y, ya[0].y);
      ya[0].z = fmaf(u0[j], w.z, ya[0].z); ya[0].w = fmaf(u0[j], w.w, ya[0].w);
      ya[1].x = fmaf(u1[j], w.x, ya[1].x); ya[1].y = fmaf(u1[j], w.y, ya[1].y);
      ya[1].z = fmaf(u1[j], w.z, ya[1].z); ya[1].w = fmaf(u1[j], w.w, ya[1].w);
      ya[2].x = fmaf(u2[j], w.x, ya[2].x); ya[2].y = fmaf(u2[j], w.y, ya[2].y);
      ya[2].z = fmaf(u2[j], w.z, ya[2].z); ya[2].w = fmaf(u2[j], w.w, ya[2].w);
      ya[3].x = fmaf(u3[j], w.x, ya[3].x); ya[3].y = fmaf(u3[j], w.y, ya[3].y);
      ya[3].z = fmaf(u3[j], w.z, ya[3].z); ya[3].w = fmaf(u3[j], w.w, ya[3].w);
    }
  }

  float nmax = 0.f;
#pragma unroll
  for (int r = 0; r < 4; ++r) {
    const float4 tv = *(const float4*)&ts[r * 1024 + tid * 4];
    float4 y;
    y.x = tv.x - ya[r].x; y.y = tv.y - ya[r].y;
    y.z = tv.z - ya[r].z; y.w = tv.w - ya[r].w;
    ((float4*)a.yout)[(size_t)(r0 + r) * (D / 4) + tid] = y;
    const float4 qv = *(const float4*)&qs[r * 1024 + tid * 4];
    float4 tn, qn;
    { const float yq = y.x + qv.x, xn = fmaxf(yq, 0.f); tn.x = xn + (tv.x - y.x); qn.x = yq - xn; }
    { const float yq = y.y + qv.y, xn = fmaxf(yq, 0.f); tn.y = xn + (tv.y - y.y); qn.y = yq - xn; }
    { const float yq = y.z + qv.z, xn = fmaxf(yq, 0.f); tn.z = xn + (tv.z - y.z); qn.z = yq - xn; }
    { const float yq = y.w + qv.w, xn = fmaxf(yq, 0.f); tn.w = xn + (tv.w - y.w); qn.w = yq - xn; }
    *(float4*)&ts[r * 1024 + tid * 4] = tn;
    *(float4*)&qs[r * 1024 + tid * 4] = qn;
    nmax = fmaxf(nmax, -y.x); nmax = fmaxf(nmax, -y.y);
    nmax = fmaxf(nmax, -y.z); nmax = fmaxf(nmax, -y.w);
  }
#pragma unroll
  for (int off = 32; off > 0; off >>= 1) nmax = fmaxf(nmax, __shfl_down(nmax, off));
  if ((tid & 63) == 0) sm[RED + (tid >> 6)] = nmax;
  __syncthreads();
  if (tid == 0) {
    const float m = fmaxf(fmaxf(sm[RED], sm[RED + 1]), fmaxf(sm[RED + 2], sm[RED + 3]));
    atomicMax((int*)&a.err[base + it], __float_as_int(m));
  }
}

// one Dykstra round with per-iteration flat barrier and exact uniform break
__device__ void dyk_round(float* sm, const KArgs& a, int bid, int base, unsigned& genG) {
  const int r0 = bid * 4;
  dyk_state_init(sm, a, r0);
  for (int it = 0; it < MAXIT; ++it) {
    dyk_iter(sm, a, r0, it, base);
    fbar(a.slotsG, bid, NGA, ++genG);  // err[base+it] is final after this
    const int eb = __hip_atomic_load((int*)&a.err[base + it], __ATOMIC_RELAXED,
                                     __HIP_MEMORY_SCOPE_AGENT);
    if (__int_as_float(eb) < TOLV) break;  // yout == y(it*) already written
  }
}

// ---------------- the megakernel ----------------
__global__ __launch_bounds__(256, 1) void mega(KArgs a) {
  __shared__ alignas(16) float sm[SMF];
  const int bid = blockIdx.x;
  const int tid = threadIdx.x;
  unsigned genF = 0, genG = 0;

  // ---- joint init: t=-rho*c, perm, F/Ybuf prep, At/AAt transposes ----
  {
    const int gtid = bid * 256 + tid;
    for (int i = gtid; i < BSZ * D; i += GRID * 256) a.t[i] = -RHOV * a.c[i];
    if (gtid < D) a.perm[gtid] = gtid;
  }
  for (int vb = bid; vb < 384; vb += GRID) {
    if (vb < 256) ph_prep(sm, vb, a.L, a.Lam, a.F, a.Ybuf);
    else if (vb < 320) { const int tt = vb - 256; ph_transpose(sm, a.A, a.At, MC, D, tt & 3, tt >> 2); }
    else { const int tt = vb - 320; ph_transpose(sm, a.AA, a.AAt, D, MC, tt & 15, tt >> 4); }
  }
  fbar(a.slotsF, bid, GRID, ++genF);

  if (bid < NGA) {
    // ======== group A: round-0 Dykstra (overlaps group B's M-build) ========
    dyk_round(sm, a, bid, 0, genG);
    fbar(a.slotsF, bid, GRID, ++genF);  // join: Wm ready, yout(r0) ready
    // ======== rounds 1,2 on group A only ========
    for (int r = 1; r < N_ROUNDS; ++r) {
      ph_round(sm, a.yout, a.Wm, a.c, a.t, bid & 15, bid >> 4);  // 128 tiles, 1 each
      fbar(a.slotsG, bid, NGA, ++genG);
      dyk_round(sm, a, bid, r * MAXIT, genG);
    }
  } else {
    // ======== group B: LU (deferred swaps) + single solve pass + scatter ========
    unsigned* slotsB = a.slotsG + NGB * 16;
    const int vbid = bid - NGA;
    for (int k = 0; k < NPAN; ++k) {
      if (vbid == 0) ph_lu_diag(sm, a.F, a.perm, a.rmap, k);
      fbar(slotsB, vbid, NGB, ++genG);
      const int rem = D - (k + 1) * NBK;
      const int nvb = (rem > 0) ? (rem + 255) / 256 : 0;
      const int ntask = k + 2 * nvb;
      for (int vb = vbid; vb < ntask; vb += NGB) {
        if (vb < k) ph_leftperm(sm, a.F, a.rmap, k, vb);
        else if (vb < k + nvb) ph_l21(sm, a.F, k, vb - k);
        else ph_trsm(sm, a.F, a.rmap, k, vb - k - nvb);
      }
      fbar(slotsB, vbid, NGB, ++genG);
      if (rem > 0) {
        const int nt = rem / 64;
        for (int vb = vbid; vb < nt * nt; vb += NGB) ph_gemm_nn(sm, a.F, k, vb % nt, vb / nt);
        fbar(slotsB, vbid, NGB, ++genG);
      }
    }
    for (int k = 0; k < NPAN; ++k) {
      for (int vb = vbid; vb < 4; vb += NGB) ph_fsolve(sm, a.F, a.Ybuf, k, vb);
      fbar(slotsB, vbid, NGB, ++genG);
      const int rem = D - (k + 1) * NBK;
      if (rem > 0) {
        for (int vb = vbid; vb < 16 * (rem / 64); vb += NGB)
          ph_tn(sm, a.F, a.Ybuf, k, (k + 1) * NBK, vb & 15, vb >> 4);
        fbar(slotsB, vbid, NGB, ++genG);
      }
    }
    for (int k = NPAN - 1; k >= 0; --k) {
      for (int vb = vbid; vb < 4; vb += NGB) ph_bsolve(sm, a.F, a.Ybuf, k, vb);
      fbar(slotsB, vbid, NGB, ++genG);
      if (k > 0) {
        for (int vb = vbid; vb < 16 * k; vb += NGB)
          ph_tn(sm, a.F, a.Ybuf, k, 0, vb & 15, vb >> 4);
        fbar(slotsB, vbid, NGB, ++genG);
      }
    }
    for (int vb = vbid; vb < 4 * D; vb += NGB) ph_scatter(a.Ybuf, a.Wm, a.perm, vb);
    fbar(a.slotsF, bid, GRID, ++genF);  // join; group B done
  }
}

extern "C" void kernel_launch(void* const* d_in, const int* in_sizes, int n_in,
                              void* d_out, int out_size, void* d_ws, size_t ws_size,
                              hipStream_t stream) {
  (void)in_sizes; (void)n_in; (void)out_size; (void)ws_size;
  KArgs a;
  a.c   = (const float*)d_in[0];
  a.A   = (const float*)d_in[1];
  a.b   = (const float*)d_in[2];
  a.AA  = (const float*)d_in[3];
  a.L   = (const float*)d_in[4];
  a.Lam = (const float*)d_in[5];
  a.yout = (float*)d_out;

  // ctrl region (zeroed every call; ws is NOT re-poisoned between replays)
  char* w = (char*)d_ws;
  a.slotsF = (unsigned*)w;              // 256 x 64B
  a.slotsG = (unsigned*)(w + 16384);    // A: [0,8KB), B: [8KB,16KB)
  a.err    = (float*)(w + 32768);       // 90 slots
  a.rmap   = (int*)(w + 33280);         // 64 ints
  w += 36864;
  a.F    = (float*)w; w += (size_t)D * D * 4;
  a.Ybuf = (float*)w; w += (size_t)D * D * 4;
  a.Wm   = (float*)w; w += (size_t)D * D * 4;
  a.t    = (float*)w; w += (size_t)BSZ * D * 4;
  a.At   = (float*)w; w += (size_t)D * MC * 4;
  a.AAt  = (float*)w; w += (size_t)MC * D * 4;
  a.perm = (int*)w;   w += (size_t)D * 4;

  hipMemsetAsync(d_ws, 0, 36864, stream);
  mega<<<dim3(GRID), dim3(256), 0, stream>>>(a);
}

// Round 8
// 5863.525 us; speedup vs baseline: 2.8705x; 1.0346x over previous
//
#include <hip/hip_runtime.h>

#define D      1024
#define BSZ    512
#define MC     256
#define NBK    64
#define NPAN   16
#define N_ROUNDS 3
#define MAXIT  30
#define TOLV   0.01f
#define RHOV   3.0f
#define XRHOV  0.5f
#define GRID   256
#define NGA    128   // group A: round-0 Dykstra blocks (4 rows each)
#define NGB    128   // group B: LU/solve blocks

// dyk LDS float offsets
#define TS   0
#define QS   4096
#define US   8192
#define PART 9216
#define BS   13312
#define RED  13568
#define SMF  13600

struct KArgs {
  const float *c, *A, *b, *AA, *L, *Lam;
  float *yout, *F, *Ybuf, *Wm;
  float *t, *At, *AAt;
  int *perm, *rmap;
  unsigned *slotsF, *slotsG, *errb;
};

// ---------------- fenced flat barrier (used only where bulk data crosses blocks) ----------------
__device__ __forceinline__ void fbar(unsigned* slots, int lid, int count, unsigned target) {
  __syncthreads();
  if (threadIdx.x == 0) {
    __builtin_amdgcn_fence(__ATOMIC_RELEASE, "agent");
    __hip_atomic_store(&slots[lid * 16], target, __ATOMIC_RELAXED, __HIP_MEMORY_SCOPE_AGENT);
  }
  for (int i = threadIdx.x; i < count; i += 256)
    while (__hip_atomic_load(&slots[i * 16], __ATOMIC_RELAXED, __HIP_MEMORY_SCOPE_AGENT) < target)
      __builtin_amdgcn_s_sleep(1);
  __builtin_amdgcn_fence(__ATOMIC_ACQUIRE, "agent");
  __syncthreads();
}

// ---------------- shared tile FMA (64x64 tile, 4x4 per thread) ----------------
__device__ __forceinline__ void tile_fma(const float (*As)[68], const float (*Bs)[68],
                                         float acc[4][4], const int tx, const int ty) {
#pragma unroll 8
  for (int kk = 0; kk < 64; ++kk) {
    const float4 a4 = *(const float4*)(&As[kk][ty * 4]);
    const float4 b4 = *(const float4*)(&Bs[kk][tx * 4]);
    const float a0 = a4.x, a1 = a4.y, a2 = a4.z, a3 = a4.w;
    const float b0 = b4.x, b1 = b4.y, b2 = b4.z, b3 = b4.w;
    acc[0][0] = fmaf(a0, b0, acc[0][0]); acc[0][1] = fmaf(a0, b1, acc[0][1]);
    acc[0][2] = fmaf(a0, b2, acc[0][2]); acc[0][3] = fmaf(a0, b3, acc[0][3]);
    acc[1][0] = fmaf(a1, b0, acc[1][0]); acc[1][1] = fmaf(a1, b1, acc[1][1]);
    acc[1][2] = fmaf(a1, b2, acc[1][2]); acc[1][3] = fmaf(a1, b3, acc[1][3]);
    acc[2][0] = fmaf(a2, b0, acc[2][0]); acc[2][1] = fmaf(a2, b1, acc[2][1]);
    acc[2][2] = fmaf(a2, b2, acc[2][2]); acc[2][3] = fmaf(a2, b3, acc[2][3]);
    acc[3][0] = fmaf(a3, b0, acc[3][0]); acc[3][1] = fmaf(a3, b1, acc[3][1]);
    acc[3][2] = fmaf(a3, b2, acc[3][2]); acc[3][3] = fmaf(a3, b3, acc[3][3]);
  }
}

// ---------------- prep / transpose ----------------
__device__ void ph_prep(float* sm, int vb, const float* L, const float* Lam,
                        float* F, float* Ybuf) {
  float (*tile)[65] = (float(*)[65])sm;
  const int bi = vb >> 4, bj = vb & 15;
  const int tx = threadIdx.x & 63, ty4 = threadIdx.x >> 6;
  const int i0 = bi * 64, j0 = bj * 64;
  for (int r = ty4; r < 64; r += 4) {
    const float v = L[(size_t)(i0 + r) * D + j0 + tx];
    F[(size_t)(i0 + r) * D + j0 + tx] = v;
    tile[r][tx] = v;
  }
  __syncthreads();
  for (int r = ty4; r < 64; r += 4) {
    const int j = j0 + r;
    Ybuf[(size_t)j * D + i0 + tx] = Lam[j] * tile[tx][r];
  }
  __syncthreads();
}

__device__ void ph_transpose(float* sm, const float* src, float* dst,
                             int srows, int scols, int tr, int tc) {
  float (*tile)[65] = (float(*)[65])sm;
  const int tx = threadIdx.x & 63, ty = threadIdx.x >> 6;
  for (int r = ty; r < 64; r += 4)
    tile[r][tx] = src[(size_t)(tr * 64 + r) * scols + tc * 64 + tx];
  __syncthreads();
  for (int r = ty; r < 64; r += 4)
    dst[(size_t)(tc * 64 + r) * srows + tr * 64 + tx] = tile[tx][r];
  __syncthreads();
}

// ---------------- LU: LDS-only pivoting with deferred off-panel swaps ----------------
__device__ void ph_lu_diag(float* sm, float* F, int* perm, int* rmap, int k) {
  float (*blk)[65] = (float(*)[65])sm;
  int* pr_sh = (int*)&sm[8960];
  int* rmp   = (int*)&sm[8964];
  const int tid = threadIdx.x;
  const int c0 = k * NBK;
  for (int e = tid; e < 4096; e += 256) {
    const int r = e >> 6, c = e & 63;
    blk[r][c] = F[(size_t)(c0 + r) * D + c0 + c];
  }
  if (tid < 64) rmp[tid] = tid;
  __syncthreads();
  for (int j = 0; j < 64; ++j) {
    if (tid < 64) {
      float v = (tid >= j) ? fabsf(blk[tid][j]) : -1.0f;
      int ridx = tid;
      for (int off = 32; off > 0; off >>= 1) {
        const float ov = __shfl_down(v, off);
        const int oi = __shfl_down(ridx, off);
        if (ov > v) { v = ov; ridx = oi; }
      }
      if (tid == 0) *pr_sh = ridx;
    }
    __syncthreads();
    const int pr = *pr_sh;
    if (pr != j) {
      if (tid < 64) { const float a = blk[j][tid], b = blk[pr][tid]; blk[j][tid] = b; blk[pr][tid] = a; }
      if (tid == 0) {
        int t = perm[c0 + j]; perm[c0 + j] = perm[c0 + pr]; perm[c0 + pr] = t;
        t = rmp[j]; rmp[j] = rmp[pr]; rmp[pr] = t;
      }
    }
    __syncthreads();
    const float inv = 1.0f / blk[j][j];
    const int r = tid >> 2, l4 = tid & 3;
    if (r > j) {
      const float lval = blk[r][j] * inv;
      if (l4 == 0) blk[r][j] = lval;
      for (int c = j + 1 + l4; c < 64; c += 4)
        blk[r][c] = fmaf(-lval, blk[j][c], blk[r][c]);
    }
    __syncthreads();
  }
  for (int e = tid; e < 4096; e += 256) {
    const int r = e >> 6, c = e & 63;
    F[(size_t)(c0 + r) * D + c0 + c] = blk[r][c];
  }
  if (tid < 64) rmap[tid] = rmp[tid];
  __syncthreads();
}

__device__ void ph_leftperm(float* sm, float* F, const int* rmap, int k, int chunk) {
  float (*tile)[65] = (float(*)[65])sm;
  int* rm = (int*)&sm[8960];
  const int tid = threadIdx.x;
  const int c0 = k * NBK;
  const int col0 = chunk * 64;
  if (tid < 64) rm[tid] = rmap[tid];
  __syncthreads();
  for (int e = tid; e < 4096; e += 256) {
    const int r = e >> 6, c = e & 63;
    tile[r][c] = F[(size_t)(c0 + rm[r]) * D + col0 + c];
  }
  __syncthreads();
  for (int e = tid; e < 4096; e += 256) {
    const int r = e >> 6, c = e & 63;
    F[(size_t)(c0 + r) * D + col0 + c] = tile[r][c];
  }
}

__device__ void ph_l21(float* sm, float* F, int k, int vb) {
  const int c0 = k * NBK;
  const int row0 = c0 + NBK;
  const int nrows = D - row0;
  float (*U)[65] = (float(*)[65])sm;
  const int tid = threadIdx.x;
  for (int e = tid; e < 4096; e += 256) { const int r = e >> 6, c = e & 63; U[r][c] = F[(size_t)(c0 + r) * D + c0 + c]; }
  __syncthreads();
  const int r = vb * 256 + tid;
  if (r >= nrows) return;
  float* Arow = &F[(size_t)(row0 + r) * D + c0];
  float x[64];
#pragma unroll
  for (int i = 0; i < 16; ++i) *(float4*)&x[i * 4] = *(const float4*)&Arow[i * 4];
#pragma unroll
  for (int jj = 0; jj < 64; ++jj) {
    float s0 = 0.f, s1 = 0.f, s2 = 0.f, s3 = 0.f;
#pragma unroll
    for (int i = 0; i + 3 < jj; i += 4) {
      s0 = fmaf(x[i], U[i][jj], s0);
      s1 = fmaf(x[i + 1], U[i + 1][jj], s1);
      s2 = fmaf(x[i + 2], U[i + 2][jj], s2);
      s3 = fmaf(x[i + 3], U[i + 3][jj], s3);
    }
#pragma unroll
    for (int i = (jj / 4) * 4; i < jj; ++i) s0 = fmaf(x[i], U[i][jj], s0);
    const float a = x[jj] - ((s0 + s1) + (s2 + s3));
    x[jj] = a / U[jj][jj];
  }
#pragma unroll
  for (int i = 0; i < 16; ++i) *(float4*)&Arow[i * 4] = *(const float4*)&x[i * 4];
}

__device__ void ph_trsm(float* sm, float* F, const int* rmap, int k, int vb) {
  const int c0 = k * NBK;
  const int colstart = c0 + NBK;
  const int ncols = D - colstart;
  float (*Lw)[65] = (float(*)[65])sm;
  int* rm = (int*)&sm[8960];
  const int tid = threadIdx.x;
  for (int e = tid; e < 4096; e += 256) { const int r = e >> 6, c = e & 63; Lw[r][c] = F[(size_t)(c0 + r) * D + c0 + c]; }
  if (tid < 64) rm[tid] = rmap[tid];
  __syncthreads();
  const int cidx = vb * 256 + tid;
  if (cidx >= ncols) return;
  const int col = colstart + cidx;
  float x[64];
#pragma unroll
  for (int i = 0; i < 64; ++i) x[i] = F[(size_t)(c0 + rm[i]) * D + col];
#pragma unroll
  for (int i = 0; i < 64; ++i) {
    float s0 = 0.f, s1 = 0.f, s2 = 0.f, s3 = 0.f;
#pragma unroll
    for (int j = 0; j + 3 < i; j += 4) {
      s0 = fmaf(Lw[i][j], x[j], s0);
      s1 = fmaf(Lw[i][j + 1], x[j + 1], s1);
      s2 = fmaf(Lw[i][j + 2], x[j + 2], s2);
      s3 = fmaf(Lw[i][j + 3], x[j + 3], s3);
    }
#pragma unroll
    for (int j = (i / 4) * 4; j < i; ++j) s0 = fmaf(Lw[i][j], x[j], s0);
    x[i] = x[i] - ((s0 + s1) + (s2 + s3));
  }
#pragma unroll
  for (int i = 0; i < 64; ++i) F[(size_t)(c0 + i) * D + col] = x[i];
}

__device__ void ph_gemm_nn(float* sm, float* F, int k, int vbx, int vby) {
  const int c0 = k * NBK;
  const int o = c0 + NBK;
  float (*As)[68] = (float(*)[68])sm;
  float (*Bs)[68] = (float(*)[68])&sm[4352];
  const int tid = threadIdx.x;
  const int cc0 = o + vbx * 64;
  const int r0 = o + vby * 64;
  for (int e = tid; e < 4096; e += 256) {
    const int r = e >> 6, c = e & 63;
    As[c][r] = F[(size_t)(r0 + r) * D + c0 + c];
    Bs[r][c] = F[(size_t)(c0 + r) * D + cc0 + c];
  }
  __syncthreads();
  float acc[4][4] = {};
  tile_fma(As, Bs, acc, tid & 15, tid >> 4);
  const int tx = tid & 15, ty = tid >> 4;
  for (int i = 0; i < 4; ++i)
    for (int j = 0; j < 4; ++j)
      F[(size_t)(r0 + ty * 4 + i) * D + cc0 + tx * 4 + j] -= acc[i][j];
  __syncthreads();
}

__device__ void ph_fsolve(float* sm, const float* F, float* Y, int k, int vb) {
  float (*T)[65] = (float(*)[65])sm;
  const int tid = threadIdx.x;
  const int c0 = k * NBK;
  for (int e = tid; e < 4096; e += 256) { const int r = e >> 6, c = e & 63; T[c][r] = F[(size_t)(c0 + r) * D + c0 + c]; }
  __syncthreads();
  const int col = vb * 256 + tid;
  float x[64];
#pragma unroll
  for (int i = 0; i < 64; ++i) x[i] = Y[(size_t)(c0 + i) * D + col];
#pragma unroll
  for (int i = 0; i < 64; ++i) {
    float s0 = 0.f, s1 = 0.f, s2 = 0.f, s3 = 0.f;
#pragma unroll
    for (int j = 0; j + 3 < i; j += 4) {
      s0 = fmaf(T[i][j], x[j], s0);
      s1 = fmaf(T[i][j + 1], x[j + 1], s1);
      s2 = fmaf(T[i][j + 2], x[j + 2], s2);
      s3 = fmaf(T[i][j + 3], x[j + 3], s3);
    }
#pragma unroll
    for (int j = (i / 4) * 4; j < i; ++j) s0 = fmaf(T[i][j], x[j], s0);
    const float a = x[i] - ((s0 + s1) + (s2 + s3));
    x[i] = a / T[i][i];
  }
#pragma unroll
  for (int i = 0; i < 64; ++i) Y[(size_t)(c0 + i) * D + col] = x[i];
  __syncthreads();
}

__device__ void ph_bsolve(float* sm, const float* F, float* Y, int k, int vb) {
  float (*T)[65] = (float(*)[65])sm;
  const int tid = threadIdx.x;
  const int c0 = k * NBK;
  for (int e = tid; e < 4096; e += 256) { const int r = e >> 6, c = e & 63; T[c][r] = F[(size_t)(c0 + r) * D + c0 + c]; }
  __syncthreads();
  const int col = vb * 256 + tid;
  float x[64];
#pragma unroll
  for (int i = 0; i < 64; ++i) x[i] = Y[(size_t)(c0 + i) * D + col];
#pragma unroll
  for (int i = 63; i >= 0; --i) {
    float s0 = 0.f, s1 = 0.f, s2 = 0.f, s3 = 0.f;
#pragma unroll
    for (int j = i + 1; j + 3 < 64; j += 4) {
      s0 = fmaf(T[i][j], x[j], s0);
      s1 = fmaf(T[i][j + 1], x[j + 1], s1);
      s2 = fmaf(T[i][j + 2], x[j + 2], s2);
      s3 = fmaf(T[i][j + 3], x[j + 3], s3);
    }
#pragma unroll
    for (int j = i + 1 + (((63 - i) / 4) * 4); j < 64; ++j) s0 = fmaf(T[i][j], x[j], s0);
    x[i] = x[i] - ((s0 + s1) + (s2 + s3));
  }
#pragma unroll
  for (int i = 0; i < 64; ++i) Y[(size_t)(c0 + i) * D + col] = x[i];
  __syncthreads();
}

__device__ void ph_tn(float* sm, const float* F, float* Y, int k, int rlo, int vbx, int vby) {
  const int c0 = k * NBK;
  float (*As)[68] = (float(*)[68])sm;
  float (*Bs)[68] = (float(*)[68])&sm[4352];
  const int tid = threadIdx.x;
  const int cc0 = vbx * 64;
  const int r0 = rlo + vby * 64;
  for (int e = tid; e < 4096; e += 256) {
    const int r = e >> 6, c = e & 63;
    As[r][c] = F[(size_t)(c0 + r) * D + r0 + c];
    Bs[r][c] = Y[(size_t)(c0 + r) * D + cc0 + c];
  }
  __syncthreads();
  float acc[4][4] = {};
  tile_fma(As, Bs, acc, tid & 15, tid >> 4);
  const int tx = tid & 15, ty = tid >> 4;
  for (int i = 0; i < 4; ++i)
    for (int j = 0; j < 4; ++j)
      Y[(size_t)(r0 + ty * 4 + i) * D + cc0 + tx * 4 + j] -= acc[i][j];
  __syncthreads();
}

__device__ void ph_scatter(const float* Y, float* Wm, const int* perm, int vb) {
  const int i = vb >> 2;
  const int c = (vb & 3) * 256 + threadIdx.x;
  Wm[(size_t)perm[i] * D + c] = Y[(size_t)i * D + c];
}

__device__ void ph_round(float* sm, const float* yout, const float* Wm, const float* cmat,
                         float* t, int vbx, int vby) {
  float (*As)[68] = (float(*)[68])sm;
  float (*Bs)[68] = (float(*)[68])&sm[4352];
  const int tid = threadIdx.x;
  const int i0 = vbx * 64;
  const int b0 = vby * 64;
  float acc[4][4] = {};
  for (int kb = 0; kb < D; kb += 64) {
    for (int e = tid; e < 4096; e += 256) {
      const int r = e >> 6, c = e & 63;
      As[c][r] = yout[(size_t)(b0 + r) * D + kb + c];
      Bs[r][c] = Wm[(size_t)(kb + r) * D + i0 + c];
    }
    __syncthreads();
    tile_fma(As, Bs, acc, tid & 15, tid >> 4);
    __syncthreads();
  }
  const int tx = tid & 15, ty = tid >> 4;
  for (int i = 0; i < 4; ++i)
    for (int j = 0; j < 4; ++j) {
      const int b = b0 + ty * 4 + i, col = i0 + tx * 4 + j;
      const float v = yout[(size_t)b * D + col] - XRHOV * acc[i][j] - RHOV * cmat[(size_t)b * D + col];
      t[(size_t)b * D + col] = v;
    }
  __syncthreads();
}

// ---------------- block-local Dykstra, templated on rows-per-block ----------------
template <int R>
__device__ void dyk_state_init(float* sm, const KArgs& a, int r0) {
  float4* ts4 = (float4*)(sm + TS);
  float4* qs4 = (float4*)(sm + QS);
  const float4* t4 = (const float4*)(a.t + (size_t)r0 * D);
  for (int e = threadIdx.x; e < R * 256; e += 256) {
    ts4[e] = t4[e];
    qs4[e] = make_float4(0.f, 0.f, 0.f, 0.f);
  }
  sm[BS + threadIdx.x] = a.b[threadIdx.x];
  __syncthreads();
}

template <int R>
__device__ void dyk_iter(float* sm, const KArgs& a, int r0) {
  const int tid = threadIdx.x;
  float* ts = sm + TS;
  float* qs = sm + QS;
  float* us = sm + US;
  float* part = sm + PART;

  // u-phase: part[ks][r][m] = sum over k-quarter of ts[r][k]*At[k][m]
  const int m4 = tid & 63, ks = tid >> 6;
  const float* AtB = a.At + (size_t)ks * 256 * MC + m4 * 4;
  float4 ua[R];
#pragma unroll
  for (int r = 0; r < R; ++r) ua[r] = make_float4(0.f, 0.f, 0.f, 0.f);
  const int kb = ks * 256;
#pragma unroll 2
  for (int k4 = 0; k4 < 64; ++k4) {
    float tr[R][4];
#pragma unroll
    for (int r = 0; r < R; ++r) *(float4*)tr[r] = *(const float4*)&ts[r * 1024 + kb + k4 * 4];
#pragma unroll
    for (int j = 0; j < 4; ++j) {
      const float4 av = *(const float4*)(AtB + (size_t)(k4 * 4 + j) * MC);
#pragma unroll
      for (int r = 0; r < R; ++r) {
        ua[r].x = fmaf(tr[r][j], av.x, ua[r].x);
        ua[r].y = fmaf(tr[r][j], av.y, ua[r].y);
        ua[r].z = fmaf(tr[r][j], av.z, ua[r].z);
        ua[r].w = fmaf(tr[r][j], av.w, ua[r].w);
      }
    }
  }
#pragma unroll
  for (int r = 0; r < R; ++r) ((float4*)part)[(ks * R + r) * 64 + m4] = ua[r];
  __syncthreads();

  // reduce partials: us[r][m] = sum_ks part - b[m]
  {
    const int m = tid;
#pragma unroll
    for (int r = 0; r < R; ++r)
      us[r * 256 + m] = part[(0 * R + r) * 256 + m] + part[(1 * R + r) * 256 + m] +
                        part[(2 * R + r) * 256 + m] + part[(3 * R + r) * 256 + m] - sm[BS + m];
  }
  __syncthreads();

  // y-phase: y[r][d] = ts[r][d] - sum_m us[r][m]*AAt[m][d]
  float4 ya[R];
#pragma unroll
  for (int r = 0; r < R; ++r) ya[r] = make_float4(0.f, 0.f, 0.f, 0.f);
  const float4* AAB = (const float4*)a.AAt;
#pragma unroll 2
  for (int mi = 0; mi < 64; ++mi) {
    float ur[R][4];
#pragma unroll
    for (int r = 0; r < R; ++r) *(float4*)ur[r] = *(const float4*)&us[r * 256 + mi * 4];
#pragma unroll
    for (int j = 0; j < 4; ++j) {
      const float4 w = AAB[(size_t)(mi * 4 + j) * (D / 4) + tid];
#pragma unroll
      for (int r = 0; r < R; ++r) {
        ya[r].x = fmaf(ur[r][j], w.x, ya[r].x);
        ya[r].y = fmaf(ur[r][j], w.y, ya[r].y);
        ya[r].z = fmaf(ur[r][j], w.z, ya[r].z);
        ya[r].w = fmaf(ur[r][j], w.w, ya[r].w);
      }
    }
  }

  float nmax = 0.f;
#pragma unroll
  for (int r = 0; r < R; ++r) {
    const float4 tv = *(const float4*)&ts[r * 1024 + tid * 4];
    float4 y;
    y.x = tv.x - ya[r].x; y.y = tv.y - ya[r].y;
    y.z = tv.z - ya[r].z; y.w = tv.w - ya[r].w;
    ((float4*)a.yout)[(size_t)(r0 + r) * (D / 4) + tid] = y;
    const float4 qv = *(const float4*)&qs[r * 1024 + tid * 4];
    float4 tn, qn;
    { const float yq = y.x + qv.x, xn = fmaxf(yq, 0.f); tn.x = xn + (tv.x - y.x); qn.x = yq - xn; }
    { const float yq = y.y + qv.y, xn = fmaxf(yq, 0.f); tn.y = xn + (tv.y - y.y); qn.y = yq - xn; }
    { const float yq = y.z + qv.z, xn = fmaxf(yq, 0.f); tn.z = xn + (tv.z - y.z); qn.z = yq - xn; }
    { const float yq = y.w + qv.w, xn = fmaxf(yq, 0.f); tn.w = xn + (tv.w - y.w); qn.w = yq - xn; }
    *(float4*)&ts[r * 1024 + tid * 4] = tn;
    *(float4*)&qs[r * 1024 + tid * 4] = qn;
    nmax = fmaxf(nmax, -y.x); nmax = fmaxf(nmax, -y.y);
    nmax = fmaxf(nmax, -y.z); nmax = fmaxf(nmax, -y.w);
  }
#pragma unroll
  for (int off = 32; off > 0; off >>= 1) nmax = fmaxf(nmax, __shfl_down(nmax, off));
  if ((tid & 63) == 0) sm[RED + (tid >> 6)] = nmax;
  __syncthreads();
}

// fence-free round: per-iteration sync via per-block err slots (atomics only)
template <int R>
__device__ void dyk_round(float* sm, const KArgs& a, int bid, int nblk, int base) {
  const int r0 = bid * R;
  dyk_state_init<R>(sm, a, r0);
  for (int it = 0; it < MAXIT; ++it) {
    dyk_iter<R>(sm, a, r0);
    if (threadIdx.x == 0) {
      const float bmax = fmaxf(fmaxf(sm[RED], sm[RED + 1]), fmaxf(sm[RED + 2], sm[RED + 3]));
      __hip_atomic_store(&a.errb[(size_t)(base + it) * GRID + bid],
                         __float_as_uint(bmax) | 0x80000000u,
                         __ATOMIC_RELAXED, __HIP_MEMORY_SCOPE_AGENT);
    }
    float v = 0.f;
    if (threadIdx.x < nblk) {
      unsigned u = __hip_atomic_load(&a.errb[(size_t)(base + it) * GRID + threadIdx.x],
                                     __ATOMIC_RELAXED, __HIP_MEMORY_SCOPE_AGENT);
      while (!(u & 0x80000000u)) {
        __builtin_amdgcn_s_sleep(1);
        u = __hip_atomic_load(&a.errb[(size_t)(base + it) * GRID + threadIdx.x],
                              __ATOMIC_RELAXED, __HIP_MEMORY_SCOPE_AGENT);
      }
      v = __uint_as_float(u & 0x7FFFFFFFu);
    }
#pragma unroll
    for (int off = 32; off > 0; off >>= 1) v = fmaxf(v, __shfl_down(v, off));
    __syncthreads();  // thread0's read of RED above is done before overwrite
    if ((threadIdx.x & 63) == 0) sm[RED + (threadIdx.x >> 6)] = v;
    __syncthreads();
    const float gmax = fmaxf(fmaxf(sm[RED], sm[RED + 1]), fmaxf(sm[RED + 2], sm[RED + 3]));
    __syncthreads();
    if (gmax < TOLV) break;  // uniform: same posted set for every block
  }
}

// ---------------- the megakernel ----------------
__global__ __launch_bounds__(256, 1) void mega(KArgs a) {
  __shared__ alignas(16) float sm[SMF];
  const int bid = blockIdx.x;
  const int tid = threadIdx.x;
  unsigned genF = 0, genG = 0;

  // ---- joint init: t=-rho*c, perm, F/Ybuf prep, At/AAt transposes ----
  {
    const int gtid = bid * 256 + tid;
    for (int i = gtid; i < BSZ * D; i += GRID * 256) a.t[i] = -RHOV * a.c[i];
    if (gtid < D) a.perm[gtid] = gtid;
  }
  for (int vb = bid; vb < 384; vb += GRID) {
    if (vb < 256) ph_prep(sm, vb, a.L, a.Lam, a.F, a.Ybuf);
    else if (vb < 320) { const int tt = vb - 256; ph_transpose(sm, a.A, a.At, MC, D, tt & 3, tt >> 2); }
    else { const int tt = vb - 320; ph_transpose(sm, a.AA, a.AAt, D, MC, tt & 15, tt >> 4); }
  }
  fbar(a.slotsF, bid, GRID, ++genF);

  if (bid < NGA) {
    // ======== group A: round-0 Dykstra (overlaps group B's M-build) ========
    dyk_round<4>(sm, a, bid, NGA, 0);
    fbar(a.slotsF, bid, GRID, ++genF);  // join: Wm ready, yout ready
  } else {
    // ======== group B: LU (deferred swaps) + single solve pass + scatter ========
    unsigned* slotsB = a.slotsG + NGB * 16;
    const int vbid = bid - NGA;
    for (int k = 0; k < NPAN; ++k) {
      if (vbid == 0) ph_lu_diag(sm, a.F, a.perm, a.rmap, k);
      fbar(slotsB, vbid, NGB, ++genG);
      const int rem = D - (k + 1) * NBK;
      const int nvb = (rem > 0) ? (rem + 255) / 256 : 0;
      const int ntask = k + 2 * nvb;
      for (int vb = vbid; vb < ntask; vb += NGB) {
        if (vb < k) ph_leftperm(sm, a.F, a.rmap, k, vb);
        else if (vb < k + nvb) ph_l21(sm, a.F, k, vb - k);
        else ph_trsm(sm, a.F, a.rmap, k, vb - k - nvb);
      }
      fbar(slotsB, vbid, NGB, ++genG);
      if (rem > 0) {
        const int nt = rem / 64;
        for (int vb = vbid; vb < nt * nt; vb += NGB) ph_gemm_nn(sm, a.F, k, vb % nt, vb / nt);
        fbar(slotsB, vbid, NGB, ++genG);
      }
    }
    for (int k = 0; k < NPAN; ++k) {
      for (int vb = vbid; vb < 4; vb += NGB) ph_fsolve(sm, a.F, a.Ybuf, k, vb);
      fbar(slotsB, vbid, NGB, ++genG);
      const int rem = D - (k + 1) * NBK;
      if (rem > 0) {
        for (int vb = vbid; vb < 16 * (rem / 64); vb += NGB)
          ph_tn(sm, a.F, a.Ybuf, k, (k + 1) * NBK, vb & 15, vb >> 4);
        fbar(slotsB, vbid, NGB, ++genG);
      }
    }
    for (int k = NPAN - 1; k >= 0; --k) {
      for (int vb = vbid; vb < 4; vb += NGB) ph_bsolve(sm, a.F, a.Ybuf, k, vb);
      fbar(slotsB, vbid, NGB, ++genG);
      if (k > 0) {
        for (int vb = vbid; vb < 16 * k; vb += NGB)
          ph_tn(sm, a.F, a.Ybuf, k, 0, vb & 15, vb >> 4);
        fbar(slotsB, vbid, NGB, ++genG);
      }
    }
    for (int vb = vbid; vb < 4 * D; vb += NGB) ph_scatter(a.Ybuf, a.Wm, a.perm, vb);
    fbar(a.slotsF, bid, GRID, ++genF);  // join
  }

  // ======== rounds 1,2: full grid, 2 rows/block, fence-free Dykstra sync ========
  for (int r = 1; r < N_ROUNDS; ++r) {
    if (bid < 128) ph_round(sm, a.yout, a.Wm, a.c, a.t, bid & 15, bid >> 4);
    fbar(a.slotsF, bid, GRID, ++genF);  // t ready (bulk data -> fenced)
    dyk_round<2>(sm, a, bid, GRID, r * MAXIT);
    if (r + 1 < N_ROUNDS)
      fbar(a.slotsF, bid, GRID, ++genF);  // yout ready for next ph_round
  }
}

extern "C" void kernel_launch(void* const* d_in, const int* in_sizes, int n_in,
                              void* d_out, int out_size, void* d_ws, size_t ws_size,
                              hipStream_t stream) {
  (void)in_sizes; (void)n_in; (void)out_size; (void)ws_size;
  KArgs a;
  a.c   = (const float*)d_in[0];
  a.A   = (const float*)d_in[1];
  a.b   = (const float*)d_in[2];
  a.AA  = (const float*)d_in[3];
  a.L   = (const float*)d_in[4];
  a.Lam = (const float*)d_in[5];
  a.yout = (float*)d_out;

  // ctrl region (zeroed every call; ws is NOT re-poisoned between replays)
  char* w = (char*)d_ws;
  a.slotsF = (unsigned*)w;                    // 256 x 64B
  a.slotsG = (unsigned*)(w + 16384);          // B-domain barrier slots
  a.errb   = (unsigned*)(w + 32768);          // 90 x 256 posted-err slots (92160 B)
  a.rmap   = (int*)(w + 124928);              // 64 ints
  w += 131072;
  a.F    = (float*)w; w += (size_t)D * D * 4;
  a.Ybuf = (float*)w; w += (size_t)D * D * 4;
  a.Wm   = (float*)w; w += (size_t)D * D * 4;
  a.t    = (float*)w; w += (size_t)BSZ * D * 4;
  a.At   = (float*)w; w += (size_t)D * MC * 4;
  a.AAt  = (float*)w; w += (size_t)MC * D * 4;
  a.perm = (int*)w;   w += (size_t)D * 4;

  hipMemsetAsync(d_ws, 0, 131072, stream);
  mega<<<dim3(GRID), dim3(256), 0, stream>>>(a);
}